// Round 1
// baseline (33247.791 us; speedup 1.0000x reference)
//
#include <hip/hip_runtime.h>
#include <math.h>

#define NN 100000
#define EE 3200000
#define D 128

// ---------------- degree / norm ----------------
__global__ void deg_kernel(const int* __restrict__ dst, float* __restrict__ deg) {
    int e = blockIdx.x * 256 + threadIdx.x;
    if (e < EE) atomicAdd(&deg[dst[e]], 1.0f);
}

__global__ void norm_kernel(float* __restrict__ deg) {
    int i = blockIdx.x * 256 + threadIdx.x;
    if (i < NN) {
        float d = deg[i];
        d = d < 1.0f ? 1.0f : d;
        deg[i] = rsqrtf(d);
    }
}

// ---------------- scale: out[i,:] = in[i,:] * norm[i] (float4 granularity) ----
__global__ void scale_kernel(const float4* __restrict__ in, float4* __restrict__ out,
                             const float* __restrict__ norm) {
    int idx = blockIdx.x * 256 + threadIdx.x;  // over NN*32 float4s
    if (idx < NN * 32) {
        int row = idx >> 5;
        float n = norm[row];
        float4 v = in[idx];
        v.x *= n; v.y *= n; v.z *= n; v.w *= n;
        out[idx] = v;
    }
}

// ---------------- scatter-add: out[dst[e],:] += tmp[src[e],:] ----------------
// one thread per (edge, 4 columns)
__global__ void scatter_kernel(const int* __restrict__ src, const int* __restrict__ dst,
                               const float* __restrict__ tmp, float* __restrict__ out) {
    long long t = (long long)blockIdx.x * 256 + threadIdx.x;
    if (t < (long long)EE * 32) {
        int e = (int)(t >> 5);
        int c = ((int)t & 31) << 2;
        int s = src[e], d = dst[e];
        const float4 v = *(const float4*)(tmp + (size_t)s * D + c);
        float* o = out + (size_t)d * D + c;
        atomicAdd(o + 0, v.x);
        atomicAdd(o + 1, v.y);
        atomicAdd(o + 2, v.z);
        atomicAdd(o + 3, v.w);
    }
}

// ---------------- relu(H @ W + b), one row per block --------------------------
__global__ __launch_bounds__(128) void gemm_relu(const float* __restrict__ H,
                                                 const float* __restrict__ W,
                                                 const float* __restrict__ b,
                                                 float* __restrict__ out) {
    __shared__ float hrow[D];
    int row = blockIdx.x;
    int j = threadIdx.x;
    hrow[j] = H[(size_t)row * D + j];
    __syncthreads();
    float acc = b[j];
#pragma unroll 16
    for (int k = 0; k < D; ++k)
        acc = fmaf(hrow[k], W[k * D + j], acc);
    out[(size_t)row * D + j] = acc > 0.0f ? acc : 0.0f;
}

// ---------------- relu(H @ W + b) fused with column-sum ----------------------
#define RPB 64
__global__ __launch_bounds__(128) void gemm_relu_colsum(const float* __restrict__ H,
                                                        const float* __restrict__ W,
                                                        const float* __restrict__ b,
                                                        float* __restrict__ colsum) {
    __shared__ float hrow[D];
    int j = threadIdx.x;
    int r0 = blockIdx.x * RPB;
    int r1 = r0 + RPB;
    if (r1 > NN) r1 = NN;
    float sum = 0.0f;
    for (int r = r0; r < r1; ++r) {
        __syncthreads();
        hrow[j] = H[(size_t)r * D + j];
        __syncthreads();
        float acc = b[j];
#pragma unroll 16
        for (int k = 0; k < D; ++k)
            acc = fmaf(hrow[k], W[k * D + j], acc);
        sum += fmaxf(acc, 0.0f);
    }
    atomicAdd(&colsum[j], sum);
}

// ---------------- final tiny MLP + sigmoid -----------------------------------
__global__ __launch_bounds__(128) void final_mlp(const float* __restrict__ colsum,
                                                 const float* __restrict__ Wf1,
                                                 const float* __restrict__ bf1,
                                                 const float* __restrict__ Wf2,
                                                 const float* __restrict__ bf2,
                                                 float* __restrict__ out) {
    __shared__ float hg[D];
    __shared__ float red[D];
    int j = threadIdx.x;
    hg[j] = colsum[j] * (1.0f / (float)NN);
    __syncthreads();
    float acc = bf1[j];
#pragma unroll 16
    for (int k = 0; k < D; ++k)
        acc = fmaf(hg[k], Wf1[k * D + j], acc);
    acc = fmaxf(acc, 0.0f);
    red[j] = acc * Wf2[j];
    __syncthreads();
    for (int s = 64; s > 0; s >>= 1) {
        if (j < s) red[j] += red[j + s];
        __syncthreads();
    }
    if (j == 0) {
        float o = red[0] + bf2[0];
        o = fmaxf(o, 0.0f);
        out[0] = 1.0f / (1.0f + expf(-o));
    }
}

// ---------------- launch ------------------------------------------------------
extern "C" void kernel_launch(void* const* d_in, const int* in_sizes, int n_in,
                              void* d_out, int out_size, void* d_ws, size_t ws_size,
                              hipStream_t stream) {
    const float* x   = (const float*)d_in[0];
    const int*   src = (const int*)d_in[1];
    const int*   dst = (const int*)d_in[2];
    const float* W1  = (const float*)d_in[3];
    const float* b1  = (const float*)d_in[4];
    const float* W2  = (const float*)d_in[5];
    const float* b2  = (const float*)d_in[6];
    const float* Wf1 = (const float*)d_in[7];
    const float* bf1 = (const float*)d_in[8];
    const float* Wf2 = (const float*)d_in[9];
    const float* bf2 = (const float*)d_in[10];
    float* out = (float*)d_out;

    char* ws = (char*)d_ws;
    constexpr size_t OFF_NORM = 0;                       // NN floats
    constexpr size_t OFF_A    = 400128;                  // NN*D floats
    constexpr size_t OFF_B    = OFF_A + (size_t)NN * D * 4;
    constexpr size_t OFF_CS   = OFF_B + (size_t)NN * D * 4;
    float* norm   = (float*)(ws + OFF_NORM);
    float* bufA   = (float*)(ws + OFF_A);
    float* bufB   = (float*)(ws + OFF_B);
    float* colsum = (float*)(ws + OFF_CS);

    const int nThreads = 256;
    const int gridE   = (EE + nThreads - 1) / nThreads;          // deg
    const int gridN   = (NN + nThreads - 1) / nThreads;          // norm
    const int gridS   = (NN * 32 + nThreads - 1) / nThreads;     // scale
    const long long scatterT = (long long)EE * 32;
    const int gridSc  = (int)((scatterT + nThreads - 1) / nThreads);

    // degree + norm
    hipMemsetAsync(norm, 0, (size_t)NN * 4, stream);
    deg_kernel<<<gridE, nThreads, 0, stream>>>(dst, norm);
    norm_kernel<<<gridN, nThreads, 0, stream>>>(norm);

    // propagation block 1: x -> bufB (3 rounds)
    // round structure: TMP = in*norm; OUT=0; scatter TMP->OUT; OUT *= norm
    {
        const float* hin = x;
        for (int k = 0; k < 3; ++k) {
            scale_kernel<<<gridS, nThreads, 0, stream>>>((const float4*)hin, (float4*)bufA, norm);
            hipMemsetAsync(bufB, 0, (size_t)NN * D * 4, stream);
            scatter_kernel<<<gridSc, nThreads, 0, stream>>>(src, dst, bufA, bufB);
            scale_kernel<<<gridS, nThreads, 0, stream>>>((const float4*)bufB, (float4*)bufB, norm);
            hin = bufB;
        }
    }

    // h = relu(h @ W1 + b1): bufB -> bufA
    gemm_relu<<<NN, 128, 0, stream>>>(bufB, W1, b1, bufA);

    // propagation block 2: bufA -> bufA (3 rounds), bufB is scratch
    for (int k = 0; k < 3; ++k) {
        scale_kernel<<<gridS, nThreads, 0, stream>>>((const float4*)bufA, (float4*)bufB, norm);
        hipMemsetAsync(bufA, 0, (size_t)NN * D * 4, stream);
        scatter_kernel<<<gridSc, nThreads, 0, stream>>>(src, dst, bufB, bufA);
        scale_kernel<<<gridS, nThreads, 0, stream>>>((const float4*)bufA, (float4*)bufA, norm);
    }

    // h = relu(h @ W2 + b2) fused with column sums
    hipMemsetAsync(colsum, 0, D * 4, stream);
    gemm_relu_colsum<<<(NN + RPB - 1) / RPB, 128, 0, stream>>>(bufA, W2, b2, colsum);

    // final MLP + sigmoid
    final_mlp<<<1, 128, 0, stream>>>(colsum, Wf1, bf1, Wf2, bf2, out);
}

// Round 2
// 1987.042 us; speedup vs baseline: 16.7323x; 16.7323x over previous
//
#include <hip/hip_runtime.h>
#include <math.h>

#define NN 100000
#define EE 3200000
#define D 128
#define CHUNK 2048
#define NCHUNK ((NN + CHUNK - 1) / CHUNK)   // 49

// ---------------- degree count (int) ----------------
__global__ void count_deg(const int* __restrict__ dst, int* __restrict__ deg) {
    int e = blockIdx.x * 256 + threadIdx.x;
    if (e < EE) atomicAdd(&deg[dst[e]], 1);
}

__global__ void norm_from_deg(const int* __restrict__ deg, float* __restrict__ norm) {
    int i = blockIdx.x * 256 + threadIdx.x;
    if (i < NN) {
        float d = (float)deg[i];
        d = d < 1.0f ? 1.0f : d;
        norm[i] = rsqrtf(d);
    }
}

// ---------------- exclusive scan of deg -> rowptr (3-kernel hierarchical) ----
__global__ __launch_bounds__(256) void scan_chunk(const int* __restrict__ deg,
                                                  int* __restrict__ rowptr,
                                                  int* __restrict__ blocksum) {
    __shared__ int ts[256];
    int t = threadIdx.x;
    int base = blockIdx.x * CHUNK + t * 8;
    int v[8];
    int s = 0;
#pragma unroll
    for (int k = 0; k < 8; ++k) {
        int idx = base + k;
        v[k] = (idx < NN) ? deg[idx] : 0;
        s += v[k];
    }
    ts[t] = s;
    __syncthreads();
    for (int off = 1; off < 256; off <<= 1) {
        int x = (t >= off) ? ts[t - off] : 0;
        __syncthreads();
        ts[t] += x;
        __syncthreads();
    }
    int run = ts[t] - s;  // exclusive prefix for this thread's 8 elems
#pragma unroll
    for (int k = 0; k < 8; ++k) {
        int idx = base + k;
        if (idx < NN) rowptr[idx] = run;
        run += v[k];
    }
    if (t == 255) blocksum[blockIdx.x] = ts[255];
}

__global__ void scan_blocksums(int* __restrict__ blocksum) {
    if (threadIdx.x == 0 && blockIdx.x == 0) {
        int run = 0;
        for (int i = 0; i < NCHUNK; ++i) {
            int v = blocksum[i];
            blocksum[i] = run;
            run += v;
        }
    }
}

__global__ void add_offsets(int* __restrict__ rowptr, int* __restrict__ cursor,
                            const int* __restrict__ blocksum) {
    int i = blockIdx.x * 256 + threadIdx.x;
    if (i < NN) {
        int v = rowptr[i] + blocksum[i / CHUNK];
        rowptr[i] = v;
        cursor[i] = v;
    }
    if (i == 0) rowptr[NN] = EE;
}

// ---------------- bucket edges into CSR ----------------
__global__ void bucket(const int* __restrict__ src, const int* __restrict__ dst,
                       int* __restrict__ cursor, int* __restrict__ csr) {
    int e = blockIdx.x * 256 + threadIdx.x;
    if (e < EE) {
        int pos = atomicAdd(&cursor[dst[e]], 1);
        csr[pos] = src[e];
    }
}

// ---------------- initial scale: g0 = x * norm ----------------
__global__ void scale_kernel(const float4* __restrict__ in, float4* __restrict__ out,
                             const float* __restrict__ norm) {
    int idx = blockIdx.x * 256 + threadIdx.x;
    if (idx < NN * 32) {
        int row = idx >> 5;
        float n = norm[row];
        float4 v = in[idx];
        v.x *= n; v.y *= n; v.z *= n; v.w *= n;
        out[idx] = v;
    }
}

// ---------------- CSR gather: out[i,:] = mult(i) * sum_{e in row i} hs[csr[e],:]
// FINAL=0: mult = norm^2 (stays in scaled domain); FINAL=1: mult = norm (yields h)
template <int FINAL>
__global__ __launch_bounds__(128) void gather_kernel(const int* __restrict__ rowptr,
                                                     const int* __restrict__ csr,
                                                     const float* __restrict__ hs,
                                                     const float* __restrict__ norm,
                                                     float* __restrict__ out) {
    int i = blockIdx.x;
    int j = threadIdx.x;
    int p0 = rowptr[i], p1 = rowptr[i + 1];
    float acc = 0.0f;
    int p = p0;
    for (; p + 4 <= p1; p += 4) {
        int s0 = csr[p], s1 = csr[p + 1], s2 = csr[p + 2], s3 = csr[p + 3];
        float a0 = hs[(size_t)s0 * D + j];
        float a1 = hs[(size_t)s1 * D + j];
        float a2 = hs[(size_t)s2 * D + j];
        float a3 = hs[(size_t)s3 * D + j];
        acc += (a0 + a1) + (a2 + a3);
    }
    for (; p < p1; ++p) acc += hs[(size_t)csr[p] * D + j];
    float n = norm[i];
    float m = FINAL ? n : n * n;
    out[(size_t)i * D + j] = acc * m;
}

// ---------------- relu(H @ W + b) * norm, 8 rows at a time ----------------
#define GR 8
#define GRPB 32
__global__ __launch_bounds__(128) void gemm_relu_scale(const float* __restrict__ H,
                                                       const float* __restrict__ W,
                                                       const float* __restrict__ b,
                                                       const float* __restrict__ norm,
                                                       float* __restrict__ out) {
    __shared__ float hs[GR][D];
    int j = threadIdx.x;
    float bj = b[j];
    int rend = blockIdx.x * GRPB + GRPB;
    for (int r0 = blockIdx.x * GRPB; r0 < rend; r0 += GR) {
        __syncthreads();
#pragma unroll
        for (int r = 0; r < GR; ++r) hs[r][j] = H[(size_t)(r0 + r) * D + j];
        __syncthreads();
        float acc[GR];
#pragma unroll
        for (int r = 0; r < GR; ++r) acc[r] = bj;
        for (int k = 0; k < D; ++k) {
            float w = W[k * D + j];
#pragma unroll
            for (int r = 0; r < GR; ++r) acc[r] = fmaf(hs[r][k], w, acc[r]);
        }
#pragma unroll
        for (int r = 0; r < GR; ++r)
            out[(size_t)(r0 + r) * D + j] = fmaxf(acc[r], 0.0f) * norm[r0 + r];
    }
}

// ---------------- relu(H @ W + b) fused with column-sum ----------------
__global__ __launch_bounds__(128) void gemm_relu_colsum(const float* __restrict__ H,
                                                        const float* __restrict__ W,
                                                        const float* __restrict__ b,
                                                        float* __restrict__ colsum) {
    __shared__ float hs[GR][D];
    int j = threadIdx.x;
    float bj = b[j];
    float sum = 0.0f;
    int rend = blockIdx.x * GRPB + GRPB;
    for (int r0 = blockIdx.x * GRPB; r0 < rend; r0 += GR) {
        __syncthreads();
#pragma unroll
        for (int r = 0; r < GR; ++r) hs[r][j] = H[(size_t)(r0 + r) * D + j];
        __syncthreads();
        float acc[GR];
#pragma unroll
        for (int r = 0; r < GR; ++r) acc[r] = bj;
        for (int k = 0; k < D; ++k) {
            float w = W[k * D + j];
#pragma unroll
            for (int r = 0; r < GR; ++r) acc[r] = fmaf(hs[r][k], w, acc[r]);
        }
#pragma unroll
        for (int r = 0; r < GR; ++r) sum += fmaxf(acc[r], 0.0f);
    }
    atomicAdd(&colsum[j], sum);
}

// ---------------- final tiny MLP + sigmoid ----------------
__global__ __launch_bounds__(128) void final_mlp(const float* __restrict__ colsum,
                                                 const float* __restrict__ Wf1,
                                                 const float* __restrict__ bf1,
                                                 const float* __restrict__ Wf2,
                                                 const float* __restrict__ bf2,
                                                 float* __restrict__ out) {
    __shared__ float hg[D];
    __shared__ float red[D];
    int j = threadIdx.x;
    hg[j] = colsum[j] * (1.0f / (float)NN);
    __syncthreads();
    float acc = bf1[j];
#pragma unroll 16
    for (int k = 0; k < D; ++k)
        acc = fmaf(hg[k], Wf1[k * D + j], acc);
    acc = fmaxf(acc, 0.0f);
    red[j] = acc * Wf2[j];
    __syncthreads();
    for (int s = 64; s > 0; s >>= 1) {
        if (j < s) red[j] += red[j + s];
        __syncthreads();
    }
    if (j == 0) {
        float o = red[0] + bf2[0];
        o = fmaxf(o, 0.0f);
        out[0] = 1.0f / (1.0f + expf(-o));
    }
}

// ---------------- launch ------------------------------------------------------
extern "C" void kernel_launch(void* const* d_in, const int* in_sizes, int n_in,
                              void* d_out, int out_size, void* d_ws, size_t ws_size,
                              hipStream_t stream) {
    const float* x   = (const float*)d_in[0];
    const int*   src = (const int*)d_in[1];
    const int*   dst = (const int*)d_in[2];
    const float* W1  = (const float*)d_in[3];
    const float* b1  = (const float*)d_in[4];
    const float* W2  = (const float*)d_in[5];
    const float* b2  = (const float*)d_in[6];
    const float* Wf1 = (const float*)d_in[7];
    const float* bf1 = (const float*)d_in[8];
    const float* Wf2 = (const float*)d_in[9];
    const float* bf2 = (const float*)d_in[10];
    float* out = (float*)d_out;

    char* ws = (char*)d_ws;
    // offsets (bytes), all 128-aligned
    constexpr size_t OFF_DEG  = 0;                         // NN ints      (400000)
    constexpr size_t OFF_RP   = 400128;                    // NN+1 ints    (400004)
    constexpr size_t OFF_CUR  = OFF_RP  + 400128;          // NN ints
    constexpr size_t OFF_BS   = OFF_CUR + 400128;          // NCHUNK ints
    constexpr size_t OFF_CSR  = OFF_BS  + 256;             // EE ints      (12.8 MB)
    constexpr size_t OFF_CS   = OFF_CSR + (size_t)EE * 4;  // D floats
    constexpr size_t OFF_A    = OFF_CS  + 512;             // NN*D floats  (51.2 MB)
    constexpr size_t OFF_B    = OFF_A   + (size_t)NN * D * 4;
    int*   deg    = (int*)(ws + OFF_DEG);
    int*   rowptr = (int*)(ws + OFF_RP);
    int*   cursor = (int*)(ws + OFF_CUR);
    int*   bsum   = (int*)(ws + OFF_BS);
    int*   csr    = (int*)(ws + OFF_CSR);
    float* colsum = (float*)(ws + OFF_CS);
    float* bufA   = (float*)(ws + OFF_A);
    float* bufB   = (float*)(ws + OFF_B);
    float* norm   = (float*)(ws + OFF_CUR);  // reuse cursor space? NO — cursor live during bucket.
    // norm must live through whole call; give it its own slot after bufB:
    norm = (float*)(ws + OFF_B + (size_t)NN * D * 4);

    const int nT = 256;
    const int gridE = (EE + nT - 1) / nT;
    const int gridN = (NN + nT - 1) / nT;
    const int gridS = (NN * 32 + nT - 1) / nT;

    // ---- CSR build + norm ----
    hipMemsetAsync(deg, 0, (size_t)NN * 4, stream);
    count_deg<<<gridE, nT, 0, stream>>>(dst, deg);
    norm_from_deg<<<gridN, nT, 0, stream>>>(deg, norm);
    scan_chunk<<<NCHUNK, 256, 0, stream>>>(deg, rowptr, bsum);
    scan_blocksums<<<1, 64, 0, stream>>>(bsum);
    add_offsets<<<gridN, nT, 0, stream>>>(rowptr, cursor, bsum);
    bucket<<<gridE, nT, 0, stream>>>(src, dst, cursor, csr);

    // ---- propagation block 1: g0 = x*norm; A,A,B rounds -> h in bufB ----
    scale_kernel<<<gridS, nT, 0, stream>>>((const float4*)x, (float4*)bufA, norm);
    gather_kernel<0><<<NN, 128, 0, stream>>>(rowptr, csr, bufA, norm, bufB);
    gather_kernel<0><<<NN, 128, 0, stream>>>(rowptr, csr, bufB, norm, bufA);
    gather_kernel<1><<<NN, 128, 0, stream>>>(rowptr, csr, bufA, norm, bufB);

    // ---- g = relu(h @ W1 + b1) * norm : bufB -> bufA ----
    gemm_relu_scale<<<NN / GRPB, 128, 0, stream>>>(bufB, W1, b1, norm, bufA);

    // ---- propagation block 2: A,A,B -> h in bufB ----
    gather_kernel<0><<<NN, 128, 0, stream>>>(rowptr, csr, bufA, norm, bufB);
    gather_kernel<0><<<NN, 128, 0, stream>>>(rowptr, csr, bufB, norm, bufA);
    gather_kernel<1><<<NN, 128, 0, stream>>>(rowptr, csr, bufA, norm, bufB);

    // ---- relu(h @ W2 + b2) + column sums ----
    hipMemsetAsync(colsum, 0, D * 4, stream);
    gemm_relu_colsum<<<NN / GRPB, 128, 0, stream>>>(bufB, W2, b2, colsum);

    // ---- final MLP + sigmoid ----
    final_mlp<<<1, 128, 0, stream>>>(colsum, Wf1, bf1, Wf2, bf2, out);
}

// Round 3
// 1436.873 us; speedup vs baseline: 23.1390x; 1.3829x over previous
//
#include <hip/hip_runtime.h>
#include <hip/hip_fp16.h>
#include <math.h>

#define NN 100000
#define EE 3200000
#define D 128
#define CHUNK 2048
#define NCHUNK ((NN + CHUNK - 1) / CHUNK)   // 49

// ---------------- degree count (int) ----------------
__global__ void count_deg(const int* __restrict__ dst, int* __restrict__ deg) {
    int e = blockIdx.x * 256 + threadIdx.x;
    if (e < EE) atomicAdd(&deg[dst[e]], 1);
}

__global__ void norm_from_deg(const int* __restrict__ deg, float* __restrict__ norm) {
    int i = blockIdx.x * 256 + threadIdx.x;
    if (i < NN) {
        float d = (float)deg[i];
        d = d < 1.0f ? 1.0f : d;
        norm[i] = rsqrtf(d);
    }
}

// ---------------- exclusive scan of deg -> rowptr ----------------
__global__ __launch_bounds__(256) void scan_chunk(const int* __restrict__ deg,
                                                  int* __restrict__ rowptr,
                                                  int* __restrict__ blocksum) {
    __shared__ int ts[256];
    int t = threadIdx.x;
    int base = blockIdx.x * CHUNK + t * 8;
    int v[8];
    int s = 0;
#pragma unroll
    for (int k = 0; k < 8; ++k) {
        int idx = base + k;
        v[k] = (idx < NN) ? deg[idx] : 0;
        s += v[k];
    }
    ts[t] = s;
    __syncthreads();
    for (int off = 1; off < 256; off <<= 1) {
        int x = (t >= off) ? ts[t - off] : 0;
        __syncthreads();
        ts[t] += x;
        __syncthreads();
    }
    int run = ts[t] - s;
#pragma unroll
    for (int k = 0; k < 8; ++k) {
        int idx = base + k;
        if (idx < NN) rowptr[idx] = run;
        run += v[k];
    }
    if (t == 255) blocksum[blockIdx.x] = ts[255];
}

__global__ void scan_blocksums(int* __restrict__ blocksum) {
    if (threadIdx.x == 0 && blockIdx.x == 0) {
        int run = 0;
        for (int i = 0; i < NCHUNK; ++i) {
            int v = blocksum[i];
            blocksum[i] = run;
            run += v;
        }
    }
}

__global__ void add_offsets(int* __restrict__ rowptr, int* __restrict__ cursor,
                            const int* __restrict__ blocksum) {
    int i = blockIdx.x * 256 + threadIdx.x;
    if (i < NN) {
        int v = rowptr[i] + blocksum[i / CHUNK];
        rowptr[i] = v;
        cursor[i] = v;
    }
    if (i == 0) rowptr[NN] = EE;
}

// ---------------- bucket edges into CSR ----------------
__global__ void bucket(const int* __restrict__ src, const int* __restrict__ dst,
                       int* __restrict__ cursor, int* __restrict__ csr) {
    int e = blockIdx.x * 256 + threadIdx.x;
    if (e < EE) {
        int pos = atomicAdd(&cursor[dst[e]], 1);
        csr[pos] = src[e];
    }
}

// ---------------- convert+scale: g0 = fp16(x * norm) ----------------
__global__ void convert_scale(const float2* __restrict__ x2, __half2* __restrict__ g,
                              const float* __restrict__ norm) {
    int idx = blockIdx.x * 256 + threadIdx.x;  // over NN*64 half2s
    if (idx < NN * 64) {
        int row = idx >> 6;
        float n = norm[row];
        float2 v = x2[idx];
        g[idx] = __floats2half2_rn(v.x * n, v.y * n);
    }
}

// ---------------- CSR gather (fp16 rows, fp32 accumulate) ----------------
// one WAVE per node; lane covers 2 columns via __half2.
// FINAL=0: out = norm^2 * sum (scaled domain); FINAL=1: out = norm * sum (= h)
template <int FINAL>
__global__ __launch_bounds__(256) void gather_half(const int* __restrict__ rowptr,
                                                   const int* __restrict__ csr,
                                                   const __half2* __restrict__ hs,
                                                   const float* __restrict__ norm,
                                                   __half2* __restrict__ out) {
    int i = blockIdx.x * 4 + (threadIdx.x >> 6);
    int lane = threadIdx.x & 63;
    int p0 = rowptr[i], p1 = rowptr[i + 1];
    float a0 = 0.0f, a1 = 0.0f;
    int p = p0;
    for (; p + 4 <= p1; p += 4) {
        int s0 = csr[p], s1 = csr[p + 1], s2 = csr[p + 2], s3 = csr[p + 3];
        __half2 v0 = hs[(size_t)s0 * 64 + lane];
        __half2 v1 = hs[(size_t)s1 * 64 + lane];
        __half2 v2 = hs[(size_t)s2 * 64 + lane];
        __half2 v3 = hs[(size_t)s3 * 64 + lane];
        a0 += (__low2float(v0) + __low2float(v1)) + (__low2float(v2) + __low2float(v3));
        a1 += (__high2float(v0) + __high2float(v1)) + (__high2float(v2) + __high2float(v3));
    }
    for (; p < p1; ++p) {
        __half2 v = hs[(size_t)csr[p] * 64 + lane];
        a0 += __low2float(v);
        a1 += __high2float(v);
    }
    float n = norm[i];
    float m = FINAL ? n : n * n;
    out[(size_t)i * 64 + lane] = __floats2half2_rn(a0 * m, a1 * m);
}

// ---------------- g_out = fp16( relu(H @ W + b) * norm ), H fp16 ----------------
#define GR 8
#define GRPB 32
__global__ __launch_bounds__(128) void gemm_relu_scale(const __half* __restrict__ H,
                                                       const float* __restrict__ W,
                                                       const float* __restrict__ b,
                                                       const float* __restrict__ norm,
                                                       __half* __restrict__ out) {
    __shared__ float hs[GR][D];
    int j = threadIdx.x;
    float bj = b[j];
    int rend = blockIdx.x * GRPB + GRPB;
    for (int r0 = blockIdx.x * GRPB; r0 < rend; r0 += GR) {
        __syncthreads();
#pragma unroll
        for (int r = 0; r < GR; ++r) hs[r][j] = __half2float(H[(size_t)(r0 + r) * D + j]);
        __syncthreads();
        float acc[GR];
#pragma unroll
        for (int r = 0; r < GR; ++r) acc[r] = bj;
        for (int k = 0; k < D; ++k) {
            float w = W[k * D + j];
#pragma unroll
            for (int r = 0; r < GR; ++r) acc[r] = fmaf(hs[r][k], w, acc[r]);
        }
#pragma unroll
        for (int r = 0; r < GR; ++r)
            out[(size_t)(r0 + r) * D + j] = __float2half_rn(fmaxf(acc[r], 0.0f) * norm[r0 + r]);
    }
}

// ---------------- relu(H @ W + b) fused with column-sum, H fp16 ----------------
__global__ __launch_bounds__(128) void gemm_relu_colsum(const __half* __restrict__ H,
                                                        const float* __restrict__ W,
                                                        const float* __restrict__ b,
                                                        float* __restrict__ colsum) {
    __shared__ float hs[GR][D];
    int j = threadIdx.x;
    float bj = b[j];
    float sum = 0.0f;
    int rend = blockIdx.x * GRPB + GRPB;
    for (int r0 = blockIdx.x * GRPB; r0 < rend; r0 += GR) {
        __syncthreads();
#pragma unroll
        for (int r = 0; r < GR; ++r) hs[r][j] = __half2float(H[(size_t)(r0 + r) * D + j]);
        __syncthreads();
        float acc[GR];
#pragma unroll
        for (int r = 0; r < GR; ++r) acc[r] = bj;
        for (int k = 0; k < D; ++k) {
            float w = W[k * D + j];
#pragma unroll
            for (int r = 0; r < GR; ++r) acc[r] = fmaf(hs[r][k], w, acc[r]);
        }
#pragma unroll
        for (int r = 0; r < GR; ++r) sum += fmaxf(acc[r], 0.0f);
    }
    atomicAdd(&colsum[j], sum);
}

// ---------------- final tiny MLP + sigmoid ----------------
__global__ __launch_bounds__(128) void final_mlp(const float* __restrict__ colsum,
                                                 const float* __restrict__ Wf1,
                                                 const float* __restrict__ bf1,
                                                 const float* __restrict__ Wf2,
                                                 const float* __restrict__ bf2,
                                                 float* __restrict__ out) {
    __shared__ float hg[D];
    __shared__ float red[D];
    int j = threadIdx.x;
    hg[j] = colsum[j] * (1.0f / (float)NN);
    __syncthreads();
    float acc = bf1[j];
#pragma unroll 16
    for (int k = 0; k < D; ++k)
        acc = fmaf(hg[k], Wf1[k * D + j], acc);
    acc = fmaxf(acc, 0.0f);
    red[j] = acc * Wf2[j];
    __syncthreads();
    for (int s = 64; s > 0; s >>= 1) {
        if (j < s) red[j] += red[j + s];
        __syncthreads();
    }
    if (j == 0) {
        float o = red[0] + bf2[0];
        o = fmaxf(o, 0.0f);
        out[0] = 1.0f / (1.0f + expf(-o));
    }
}

// ---------------- launch ------------------------------------------------------
extern "C" void kernel_launch(void* const* d_in, const int* in_sizes, int n_in,
                              void* d_out, int out_size, void* d_ws, size_t ws_size,
                              hipStream_t stream) {
    const float* x   = (const float*)d_in[0];
    const int*   src = (const int*)d_in[1];
    const int*   dst = (const int*)d_in[2];
    const float* W1  = (const float*)d_in[3];
    const float* b1  = (const float*)d_in[4];
    const float* W2  = (const float*)d_in[5];
    const float* b2  = (const float*)d_in[6];
    const float* Wf1 = (const float*)d_in[7];
    const float* bf1 = (const float*)d_in[8];
    const float* Wf2 = (const float*)d_in[9];
    const float* bf2 = (const float*)d_in[10];
    float* out = (float*)d_out;

    char* ws = (char*)d_ws;
    constexpr size_t OFF_DEG  = 0;                          // NN ints
    constexpr size_t OFF_RP   = 400128;                     // NN+1 ints
    constexpr size_t OFF_CUR  = OFF_RP  + 400128;           // NN ints
    constexpr size_t OFF_NORM = OFF_CUR + 400128;           // NN floats
    constexpr size_t OFF_BS   = OFF_NORM + 400128;          // NCHUNK ints
    constexpr size_t OFF_CS   = OFF_BS  + 256;              // D floats
    constexpr size_t OFF_CSR  = OFF_CS  + 512;              // EE ints (12.8 MB)
    constexpr size_t OFF_A    = OFF_CSR + (size_t)EE * 4;   // NN*D halfs (25.6 MB)
    constexpr size_t OFF_B    = OFF_A   + (size_t)NN * D * 2;
    int*    deg    = (int*)(ws + OFF_DEG);
    int*    rowptr = (int*)(ws + OFF_RP);
    int*    cursor = (int*)(ws + OFF_CUR);
    float*  norm   = (float*)(ws + OFF_NORM);
    int*    bsum   = (int*)(ws + OFF_BS);
    float*  colsum = (float*)(ws + OFF_CS);
    int*    csr    = (int*)(ws + OFF_CSR);
    __half* bufA   = (__half*)(ws + OFF_A);
    __half* bufB   = (__half*)(ws + OFF_B);

    const int nT = 256;
    const int gridE = (EE + nT - 1) / nT;
    const int gridN = (NN + nT - 1) / nT;
    const int gridC = (NN * 64 + nT - 1) / nT;
    const int gridG = NN / 4;  // 25000 blocks, 4 waves each, one wave per node

    // ---- CSR build + norm ----
    hipMemsetAsync(deg, 0, (size_t)NN * 4, stream);
    count_deg<<<gridE, nT, 0, stream>>>(dst, deg);
    norm_from_deg<<<gridN, nT, 0, stream>>>(deg, norm);
    scan_chunk<<<NCHUNK, 256, 0, stream>>>(deg, rowptr, bsum);
    scan_blocksums<<<1, 64, 0, stream>>>(bsum);
    add_offsets<<<gridN, nT, 0, stream>>>(rowptr, cursor, bsum);
    bucket<<<gridE, nT, 0, stream>>>(src, dst, cursor, csr);

    // ---- propagation block 1: g0 = fp16(x*norm); rounds A->B->A->B ----
    convert_scale<<<gridC, nT, 0, stream>>>((const float2*)x, (__half2*)bufA, norm);
    gather_half<0><<<gridG, 256, 0, stream>>>(rowptr, csr, (const __half2*)bufA, norm, (__half2*)bufB);
    gather_half<0><<<gridG, 256, 0, stream>>>(rowptr, csr, (const __half2*)bufB, norm, (__half2*)bufA);
    gather_half<1><<<gridG, 256, 0, stream>>>(rowptr, csr, (const __half2*)bufA, norm, (__half2*)bufB);

    // ---- g = fp16(relu(h @ W1 + b1) * norm) : bufB -> bufA ----
    gemm_relu_scale<<<NN / GRPB, 128, 0, stream>>>(bufB, W1, b1, norm, bufA);

    // ---- propagation block 2 ----
    gather_half<0><<<gridG, 256, 0, stream>>>(rowptr, csr, (const __half2*)bufA, norm, (__half2*)bufB);
    gather_half<0><<<gridG, 256, 0, stream>>>(rowptr, csr, (const __half2*)bufB, norm, (__half2*)bufA);
    gather_half<1><<<gridG, 256, 0, stream>>>(rowptr, csr, (const __half2*)bufA, norm, (__half2*)bufB);

    // ---- relu(h @ W2 + b2) + column sums ----
    hipMemsetAsync(colsum, 0, D * 4, stream);
    gemm_relu_colsum<<<NN / GRPB, 128, 0, stream>>>(bufB, W2, b2, colsum);

    // ---- final MLP + sigmoid ----
    final_mlp<<<1, 128, 0, stream>>>(colsum, Wf1, bf1, Wf2, bf2, out);
}

// Round 4
// 1115.459 us; speedup vs baseline: 29.8064x; 1.2881x over previous
//
#include <hip/hip_runtime.h>
#include <hip/hip_fp16.h>
#include <math.h>

#define NN 100000
#define EE 3200000
#define D 128
#define NB 391        // coarse buckets: node>>8, covers 391*256 = 100096 >= NN
#define NBLK 256      // blocks for coarse passes
#define ECHUNK ((EE + NBLK - 1) / NBLK)   // 12500 edges per block

// ---------------- pass 1: coarse histogram of dst>>8 ----------------
__global__ __launch_bounds__(256) void coarse_count(const int* __restrict__ dst,
                                                    int* __restrict__ coarse_cnt) {
    __shared__ int hist[NB];
    for (int i = threadIdx.x; i < NB; i += 256) hist[i] = 0;
    __syncthreads();
    int e0 = blockIdx.x * ECHUNK;
    int e1 = e0 + ECHUNK; if (e1 > EE) e1 = EE;
    for (int e = e0 + threadIdx.x; e < e1; e += 256)
        atomicAdd(&hist[dst[e] >> 8], 1);
    __syncthreads();
    for (int i = threadIdx.x; i < NB; i += 256)
        if (hist[i]) atomicAdd(&coarse_cnt[i], hist[i]);
}

// ---------------- pass 2: scan coarse counts -> offsets + cursors ----------------
__global__ __launch_bounds__(512) void coarse_scan(const int* __restrict__ coarse_cnt,
                                                   int* __restrict__ coarse_off,
                                                   int* __restrict__ coarse_cursor) {
    __shared__ int s[512];
    int t = threadIdx.x;
    int v = (t < NB) ? coarse_cnt[t] : 0;
    s[t] = v;
    __syncthreads();
    for (int off = 1; off < 512; off <<= 1) {
        int x = (t >= off) ? s[t - off] : 0;
        __syncthreads();
        s[t] += x;
        __syncthreads();
    }
    int excl = s[t] - v;
    if (t < NB) { coarse_off[t] = excl; coarse_cursor[t] = excl; }
    if (t == NB) coarse_off[NB] = excl;   // == EE
}

// ---------------- pass 3: scatter (src,dst) pairs into coarse buckets ----------------
__global__ __launch_bounds__(256) void coarse_scatter(const int* __restrict__ src,
                                                      const int* __restrict__ dst,
                                                      int* __restrict__ coarse_cursor,
                                                      int2* __restrict__ ebuf) {
    __shared__ int hist[NB];
    __shared__ int base[NB];
    for (int i = threadIdx.x; i < NB; i += 256) hist[i] = 0;
    __syncthreads();
    int e0 = blockIdx.x * ECHUNK;
    int e1 = e0 + ECHUNK; if (e1 > EE) e1 = EE;
    for (int e = e0 + threadIdx.x; e < e1; e += 256)
        atomicAdd(&hist[dst[e] >> 8], 1);
    __syncthreads();
    for (int i = threadIdx.x; i < NB; i += 256) {
        int c = hist[i];
        base[i] = c ? atomicAdd(&coarse_cursor[i], c) : 0;
    }
    __syncthreads();
    for (int e = e0 + threadIdx.x; e < e1; e += 256) {
        int d = dst[e];
        int pos = atomicAdd(&base[d >> 8], 1);
        ebuf[pos] = make_int2(src[e], d);
    }
}

// ---------------- pass 4: per-bucket fine sort -> rowptr/norm/csr ----------------
__global__ __launch_bounds__(256) void fine_sort(const int2* __restrict__ ebuf,
                                                 const int* __restrict__ coarse_off,
                                                 int* __restrict__ rowptr,
                                                 float* __restrict__ norm,
                                                 int* __restrict__ csr) {
    __shared__ int cnt[256];
    __shared__ int sbuf[256];
    int b = blockIdx.x;
    int t = threadIdx.x;
    int e0 = coarse_off[b], e1 = coarse_off[b + 1];
    int n0 = b << 8;
    cnt[t] = 0;
    __syncthreads();
    for (int e = e0 + t; e < e1; e += 256)
        atomicAdd(&cnt[ebuf[e].y & 255], 1);
    __syncthreads();
    int myc = cnt[t];
    sbuf[t] = myc;
    __syncthreads();
    for (int off = 1; off < 256; off <<= 1) {
        int x = (t >= off) ? sbuf[t - off] : 0;
        __syncthreads();
        sbuf[t] += x;
        __syncthreads();
    }
    int excl = sbuf[t] - myc;
    int node = n0 + t;
    if (node < NN) {
        rowptr[node] = e0 + excl;
        float dd = (float)myc;
        if (dd < 1.0f) dd = 1.0f;
        norm[node] = rsqrtf(dd);
    }
    cnt[t] = e0 + excl;   // reuse as cursor
    __syncthreads();
    for (int e = e0 + t; e < e1; e += 256) {
        int2 p = ebuf[e];
        int pos = atomicAdd(&cnt[p.y & 255], 1);
        csr[pos] = p.x;
    }
    if (b == 0 && t == 0) rowptr[NN] = EE;
}

// ---------------- convert+scale: g0 = fp16(x * norm) ----------------
__global__ void convert_scale(const float2* __restrict__ x2, __half2* __restrict__ g,
                              const float* __restrict__ norm) {
    int idx = blockIdx.x * 256 + threadIdx.x;  // over NN*64 half2s
    if (idx < NN * 64) {
        int row = idx >> 6;
        float n = norm[row];
        float2 v = x2[idx];
        g[idx] = __floats2half2_rn(v.x * n, v.y * n);
    }
}

// ---------------- CSR gather (fp16 rows, fp32 accumulate) ----------------
// one WAVE per node; lane covers 2 columns via __half2; unroll 8 for MLP.
template <int FINAL>
__global__ __launch_bounds__(256) void gather_half(const int* __restrict__ rowptr,
                                                   const int* __restrict__ csr,
                                                   const __half2* __restrict__ hs,
                                                   const float* __restrict__ norm,
                                                   __half2* __restrict__ out) {
    int i = blockIdx.x * 4 + (threadIdx.x >> 6);
    int lane = threadIdx.x & 63;
    int p0 = rowptr[i], p1 = rowptr[i + 1];
    float a0 = 0.0f, a1 = 0.0f;
    int p = p0;
    for (; p + 8 <= p1; p += 8) {
        int s0 = csr[p], s1 = csr[p + 1], s2 = csr[p + 2], s3 = csr[p + 3];
        int s4 = csr[p + 4], s5 = csr[p + 5], s6 = csr[p + 6], s7 = csr[p + 7];
        __half2 v0 = hs[(size_t)s0 * 64 + lane];
        __half2 v1 = hs[(size_t)s1 * 64 + lane];
        __half2 v2 = hs[(size_t)s2 * 64 + lane];
        __half2 v3 = hs[(size_t)s3 * 64 + lane];
        __half2 v4 = hs[(size_t)s4 * 64 + lane];
        __half2 v5 = hs[(size_t)s5 * 64 + lane];
        __half2 v6 = hs[(size_t)s6 * 64 + lane];
        __half2 v7 = hs[(size_t)s7 * 64 + lane];
        a0 += ((__low2float(v0) + __low2float(v1)) + (__low2float(v2) + __low2float(v3))) +
              ((__low2float(v4) + __low2float(v5)) + (__low2float(v6) + __low2float(v7)));
        a1 += ((__high2float(v0) + __high2float(v1)) + (__high2float(v2) + __high2float(v3))) +
              ((__high2float(v4) + __high2float(v5)) + (__high2float(v6) + __high2float(v7)));
    }
    for (; p < p1; ++p) {
        __half2 v = hs[(size_t)csr[p] * 64 + lane];
        a0 += __low2float(v);
        a1 += __high2float(v);
    }
    float n = norm[i];
    float m = FINAL ? n : n * n;
    out[(size_t)i * 64 + lane] = __floats2half2_rn(a0 * m, a1 * m);
}

// ---------------- g_out = fp16( relu(H @ W + b) * norm ), H fp16 ----------------
#define GR 8
#define GRPB 32
__global__ __launch_bounds__(128) void gemm_relu_scale(const __half* __restrict__ H,
                                                       const float* __restrict__ W,
                                                       const float* __restrict__ b,
                                                       const float* __restrict__ norm,
                                                       __half* __restrict__ out) {
    __shared__ float hs[GR][D];
    int j = threadIdx.x;
    float bj = b[j];
    int rend = blockIdx.x * GRPB + GRPB;
    for (int r0 = blockIdx.x * GRPB; r0 < rend; r0 += GR) {
        __syncthreads();
#pragma unroll
        for (int r = 0; r < GR; ++r) hs[r][j] = __half2float(H[(size_t)(r0 + r) * D + j]);
        __syncthreads();
        float acc[GR];
#pragma unroll
        for (int r = 0; r < GR; ++r) acc[r] = bj;
        for (int k = 0; k < D; ++k) {
            float w = W[k * D + j];
#pragma unroll
            for (int r = 0; r < GR; ++r) acc[r] = fmaf(hs[r][k], w, acc[r]);
        }
#pragma unroll
        for (int r = 0; r < GR; ++r)
            out[(size_t)(r0 + r) * D + j] = __float2half_rn(fmaxf(acc[r], 0.0f) * norm[r0 + r]);
    }
}

// ---------------- relu(H @ W + b) fused with column-sum, H fp16 ----------------
__global__ __launch_bounds__(128) void gemm_relu_colsum(const __half* __restrict__ H,
                                                        const float* __restrict__ W,
                                                        const float* __restrict__ b,
                                                        float* __restrict__ colsum) {
    __shared__ float hs[GR][D];
    int j = threadIdx.x;
    float bj = b[j];
    float sum = 0.0f;
    int rend = blockIdx.x * GRPB + GRPB;
    for (int r0 = blockIdx.x * GRPB; r0 < rend; r0 += GR) {
        __syncthreads();
#pragma unroll
        for (int r = 0; r < GR; ++r) hs[r][j] = __half2float(H[(size_t)(r0 + r) * D + j]);
        __syncthreads();
        float acc[GR];
#pragma unroll
        for (int r = 0; r < GR; ++r) acc[r] = bj;
        for (int k = 0; k < D; ++k) {
            float w = W[k * D + j];
#pragma unroll
            for (int r = 0; r < GR; ++r) acc[r] = fmaf(hs[r][k], w, acc[r]);
        }
#pragma unroll
        for (int r = 0; r < GR; ++r) sum += fmaxf(acc[r], 0.0f);
    }
    atomicAdd(&colsum[j], sum);
}

// ---------------- final tiny MLP + sigmoid ----------------
__global__ __launch_bounds__(128) void final_mlp(const float* __restrict__ colsum,
                                                 const float* __restrict__ Wf1,
                                                 const float* __restrict__ bf1,
                                                 const float* __restrict__ Wf2,
                                                 const float* __restrict__ bf2,
                                                 float* __restrict__ out) {
    __shared__ float hg[D];
    __shared__ float red[D];
    int j = threadIdx.x;
    hg[j] = colsum[j] * (1.0f / (float)NN);
    __syncthreads();
    float acc = bf1[j];
#pragma unroll 16
    for (int k = 0; k < D; ++k)
        acc = fmaf(hg[k], Wf1[k * D + j], acc);
    acc = fmaxf(acc, 0.0f);
    red[j] = acc * Wf2[j];
    __syncthreads();
    for (int s = 64; s > 0; s >>= 1) {
        if (j < s) red[j] += red[j + s];
        __syncthreads();
    }
    if (j == 0) {
        float o = red[0] + bf2[0];
        o = fmaxf(o, 0.0f);
        out[0] = 1.0f / (1.0f + expf(-o));
    }
}

// ---------------- launch ------------------------------------------------------
extern "C" void kernel_launch(void* const* d_in, const int* in_sizes, int n_in,
                              void* d_out, int out_size, void* d_ws, size_t ws_size,
                              hipStream_t stream) {
    const float* x   = (const float*)d_in[0];
    const int*   src = (const int*)d_in[1];
    const int*   dst = (const int*)d_in[2];
    const float* W1  = (const float*)d_in[3];
    const float* b1  = (const float*)d_in[4];
    const float* W2  = (const float*)d_in[5];
    const float* b2  = (const float*)d_in[6];
    const float* Wf1 = (const float*)d_in[7];
    const float* bf1 = (const float*)d_in[8];
    const float* Wf2 = (const float*)d_in[9];
    const float* bf2 = (const float*)d_in[10];
    float* out = (float*)d_out;

    char* ws = (char*)d_ws;
    constexpr size_t OFF_CC   = 0;                              // NB ints
    constexpr size_t OFF_CO   = 4096;                           // NB+1 ints
    constexpr size_t OFF_CU   = 8192;                           // NB ints
    constexpr size_t OFF_CS   = 12288;                          // D floats colsum
    constexpr size_t OFF_RP   = 16384;                          // NN+1 ints
    constexpr size_t OFF_NORM = OFF_RP + 400128;                // NN floats
    constexpr size_t OFF_EBUF = OFF_NORM + 400128;              // EE int2 (25.6 MB)
    constexpr size_t OFF_CSR  = OFF_EBUF + (size_t)EE * 8;      // EE ints (12.8 MB)
    constexpr size_t OFF_A    = OFF_CSR + (size_t)EE * 4;       // NN*D halfs (25.6 MB)
    constexpr size_t OFF_B    = OFF_A + (size_t)NN * D * 2;     // NN*D halfs
    int*    ccnt   = (int*)(ws + OFF_CC);
    int*    coff   = (int*)(ws + OFF_CO);
    int*    ccur   = (int*)(ws + OFF_CU);
    float*  colsum = (float*)(ws + OFF_CS);
    int*    rowptr = (int*)(ws + OFF_RP);
    float*  norm   = (float*)(ws + OFF_NORM);
    int2*   ebuf   = (int2*)(ws + OFF_EBUF);
    int*    csr    = (int*)(ws + OFF_CSR);
    __half* bufA   = (__half*)(ws + OFF_A);
    __half* bufB   = (__half*)(ws + OFF_B);

    const int nT = 256;
    const int gridC = (NN * 64 + nT - 1) / nT;
    const int gridG = NN / 4;  // one wave per node, 4 waves/block

    // ---- CSR build (atomic-light two-level counting sort) + norm ----
    hipMemsetAsync(ccnt, 0, (size_t)NB * 4, stream);
    coarse_count<<<NBLK, 256, 0, stream>>>(dst, ccnt);
    coarse_scan<<<1, 512, 0, stream>>>(ccnt, coff, ccur);
    coarse_scatter<<<NBLK, 256, 0, stream>>>(src, dst, ccur, ebuf);
    fine_sort<<<NB, 256, 0, stream>>>(ebuf, coff, rowptr, norm, csr);

    // ---- propagation block 1: g0 = fp16(x*norm); rounds A->B->A->B ----
    convert_scale<<<gridC, nT, 0, stream>>>((const float2*)x, (__half2*)bufA, norm);
    gather_half<0><<<gridG, 256, 0, stream>>>(rowptr, csr, (const __half2*)bufA, norm, (__half2*)bufB);
    gather_half<0><<<gridG, 256, 0, stream>>>(rowptr, csr, (const __half2*)bufB, norm, (__half2*)bufA);
    gather_half<1><<<gridG, 256, 0, stream>>>(rowptr, csr, (const __half2*)bufA, norm, (__half2*)bufB);

    // ---- g = fp16(relu(h @ W1 + b1) * norm) : bufB -> bufA ----
    gemm_relu_scale<<<NN / GRPB, 128, 0, stream>>>(bufB, W1, b1, norm, bufA);

    // ---- propagation block 2 ----
    gather_half<0><<<gridG, 256, 0, stream>>>(rowptr, csr, (const __half2*)bufA, norm, (__half2*)bufB);
    gather_half<0><<<gridG, 256, 0, stream>>>(rowptr, csr, (const __half2*)bufB, norm, (__half2*)bufA);
    gather_half<1><<<gridG, 256, 0, stream>>>(rowptr, csr, (const __half2*)bufA, norm, (__half2*)bufB);

    // ---- relu(h @ W2 + b2) + column sums ----
    hipMemsetAsync(colsum, 0, D * 4, stream);
    gemm_relu_colsum<<<NN / GRPB, 128, 0, stream>>>(bufB, W2, b2, colsum);

    // ---- final MLP + sigmoid ----
    final_mlp<<<1, 128, 0, stream>>>(colsum, Wf1, bf1, Wf2, bf2, out);
}

// Round 5
// 946.913 us; speedup vs baseline: 35.1118x; 1.1780x over previous
//
#include <hip/hip_runtime.h>
#include <hip/hip_fp16.h>
#include <math.h>

#define NN 100000
#define EE 3200000
#define D 128
#define NB 391        // coarse buckets: node>>8
#define NBLK 256
#define ECHUNK ((EE + NBLK - 1) / NBLK)
#define NSTRIP (NN / 32)   // 3125 row strips of 32

typedef _Float16 half8 __attribute__((ext_vector_type(8)));
typedef float floatx16 __attribute__((ext_vector_type(16)));

// ---------------- CSR build: coarse histogram ----------------
__global__ __launch_bounds__(256) void coarse_count(const int* __restrict__ dst,
                                                    int* __restrict__ coarse_cnt) {
    __shared__ int hist[NB];
    for (int i = threadIdx.x; i < NB; i += 256) hist[i] = 0;
    __syncthreads();
    int e0 = blockIdx.x * ECHUNK;
    int e1 = e0 + ECHUNK; if (e1 > EE) e1 = EE;
    for (int e = e0 + threadIdx.x; e < e1; e += 256)
        atomicAdd(&hist[dst[e] >> 8], 1);
    __syncthreads();
    for (int i = threadIdx.x; i < NB; i += 256)
        if (hist[i]) atomicAdd(&coarse_cnt[i], hist[i]);
}

__global__ __launch_bounds__(512) void coarse_scan(const int* __restrict__ coarse_cnt,
                                                   int* __restrict__ coarse_off,
                                                   int* __restrict__ coarse_cursor) {
    __shared__ int s[512];
    int t = threadIdx.x;
    int v = (t < NB) ? coarse_cnt[t] : 0;
    s[t] = v;
    __syncthreads();
    for (int off = 1; off < 512; off <<= 1) {
        int x = (t >= off) ? s[t - off] : 0;
        __syncthreads();
        s[t] += x;
        __syncthreads();
    }
    int excl = s[t] - v;
    if (t < NB) { coarse_off[t] = excl; coarse_cursor[t] = excl; }
    if (t == NB) coarse_off[NB] = excl;
}

__global__ __launch_bounds__(256) void coarse_scatter(const int* __restrict__ src,
                                                      const int* __restrict__ dst,
                                                      int* __restrict__ coarse_cursor,
                                                      int2* __restrict__ ebuf) {
    __shared__ int hist[NB];
    __shared__ int base[NB];
    for (int i = threadIdx.x; i < NB; i += 256) hist[i] = 0;
    __syncthreads();
    int e0 = blockIdx.x * ECHUNK;
    int e1 = e0 + ECHUNK; if (e1 > EE) e1 = EE;
    for (int e = e0 + threadIdx.x; e < e1; e += 256)
        atomicAdd(&hist[dst[e] >> 8], 1);
    __syncthreads();
    for (int i = threadIdx.x; i < NB; i += 256) {
        int c = hist[i];
        base[i] = c ? atomicAdd(&coarse_cursor[i], c) : 0;
    }
    __syncthreads();
    for (int e = e0 + threadIdx.x; e < e1; e += 256) {
        int d = dst[e];
        int pos = atomicAdd(&base[d >> 8], 1);
        ebuf[pos] = make_int2(src[e], d);
    }
}

__global__ __launch_bounds__(256) void fine_sort(const int2* __restrict__ ebuf,
                                                 const int* __restrict__ coarse_off,
                                                 int* __restrict__ rowptr,
                                                 float* __restrict__ norm,
                                                 int* __restrict__ csr) {
    __shared__ int cnt[256];
    __shared__ int sbuf[256];
    int b = blockIdx.x;
    int t = threadIdx.x;
    int e0 = coarse_off[b], e1 = coarse_off[b + 1];
    int n0 = b << 8;
    cnt[t] = 0;
    __syncthreads();
    for (int e = e0 + t; e < e1; e += 256)
        atomicAdd(&cnt[ebuf[e].y & 255], 1);
    __syncthreads();
    int myc = cnt[t];
    sbuf[t] = myc;
    __syncthreads();
    for (int off = 1; off < 256; off <<= 1) {
        int x = (t >= off) ? sbuf[t - off] : 0;
        __syncthreads();
        sbuf[t] += x;
        __syncthreads();
    }
    int excl = sbuf[t] - myc;
    int node = n0 + t;
    if (node < NN) {
        rowptr[node] = e0 + excl;
        float dd = (float)myc;
        if (dd < 1.0f) dd = 1.0f;
        norm[node] = rsqrtf(dd);
    }
    cnt[t] = e0 + excl;
    __syncthreads();
    for (int e = e0 + t; e < e1; e += 256) {
        int2 p = ebuf[e];
        int pos = atomicAdd(&cnt[p.y & 255], 1);
        csr[pos] = p.x;
    }
    if (b == 0 && t == 0) rowptr[NN] = EE;
}

// ---------------- weight convert + transpose: Wt[n*D+k] = fp16(W[k*D+n]) ------
__global__ void conv_w(const float* __restrict__ W, __half* __restrict__ Wt) {
    int idx = blockIdx.x * 256 + threadIdx.x;
    if (idx < D * D) {
        int n = idx >> 7, k = idx & 127;
        Wt[idx] = __float2half_rn(W[k * D + n]);
    }
}

// ---------------- convert+scale: g0 = fp16(x * norm) ----------------
__global__ void convert_scale(const float2* __restrict__ x2, __half2* __restrict__ g,
                              const float* __restrict__ norm) {
    int idx = blockIdx.x * 256 + threadIdx.x;
    if (idx < NN * 64) {
        int row = idx >> 6;
        float n = norm[row];
        float2 v = x2[idx];
        g[idx] = __floats2half2_rn(v.x * n, v.y * n);
    }
}

// ---------------- CSR gather: 16 lanes/node, float4 (8 fp16) per lane ---------
template <int FINAL>
__global__ __launch_bounds__(256) void gather_half(const int* __restrict__ rowptr,
                                                   const int* __restrict__ csr,
                                                   const __half* __restrict__ hs,
                                                   const float* __restrict__ norm,
                                                   __half* __restrict__ out) {
    int i = blockIdx.x * 16 + (threadIdx.x >> 4);
    int sl = threadIdx.x & 15;
    int p0 = rowptr[i], p1 = rowptr[i + 1];
    const float4* hp = (const float4*)hs;   // 16 float4 per 128-half row
    float a0 = 0, a1 = 0, a2 = 0, a3 = 0, a4 = 0, a5 = 0, a6 = 0, a7 = 0;
#define ACC(v) { const __half2* ph = (const __half2*)&(v); \
    a0 += __low2float(ph[0]); a1 += __high2float(ph[0]); \
    a2 += __low2float(ph[1]); a3 += __high2float(ph[1]); \
    a4 += __low2float(ph[2]); a5 += __high2float(ph[2]); \
    a6 += __low2float(ph[3]); a7 += __high2float(ph[3]); }
    int p = p0;
    for (; p + 4 <= p1; p += 4) {
        int s0 = csr[p], s1 = csr[p + 1], s2 = csr[p + 2], s3 = csr[p + 3];
        float4 v0 = hp[(size_t)s0 * 16 + sl];
        float4 v1 = hp[(size_t)s1 * 16 + sl];
        float4 v2 = hp[(size_t)s2 * 16 + sl];
        float4 v3 = hp[(size_t)s3 * 16 + sl];
        ACC(v0); ACC(v1); ACC(v2); ACC(v3);
    }
    for (; p < p1; ++p) {
        float4 v = hp[(size_t)csr[p] * 16 + sl];
        ACC(v);
    }
#undef ACC
    float n = norm[i];
    float m = FINAL ? n : n * n;
    float4 ov;
    __half2* oh = (__half2*)&ov;
    oh[0] = __floats2half2_rn(a0 * m, a1 * m);
    oh[1] = __floats2half2_rn(a2 * m, a3 * m);
    oh[2] = __floats2half2_rn(a4 * m, a5 * m);
    oh[3] = __floats2half2_rn(a6 * m, a7 * m);
    ((float4*)out)[(size_t)i * 16 + sl] = ov;
}

// ---------------- MFMA GEMM1: out = fp16(relu(H@W1 + b1) * norm) -------------
// wave w owns cols 32w..32w+31; B-frags preloaded from Wt (n-major fp16).
__global__ __launch_bounds__(256) void gemm1_mfma(const __half* __restrict__ H,
                                                  const __half* __restrict__ Wt,
                                                  const float* __restrict__ b,
                                                  const float* __restrict__ norm,
                                                  __half* __restrict__ out) {
    int lane = threadIdx.x & 63;
    int w = threadIdx.x >> 6;
    int m = lane & 31;
    int q = lane >> 5;
    int col = w * 32 + m;
    half8 bf[8];
    const half8* wp = (const half8*)(Wt + (size_t)col * D + q * 8);
#pragma unroll
    for (int kc = 0; kc < 8; ++kc) bf[kc] = wp[kc * 2];  // step 16 halfs
    float bc = b[col];
    for (int s = blockIdx.x; s < NSTRIP; s += gridDim.x) {
        int r0 = s * 32;
        floatx16 acc;
#pragma unroll
        for (int i = 0; i < 16; ++i) acc[i] = 0.0f;
        const half8* hp = (const half8*)(H + (size_t)(r0 + m) * D + q * 8);
#pragma unroll
        for (int kc = 0; kc < 8; ++kc)
            acc = __builtin_amdgcn_mfma_f32_32x32x16_f16(hp[kc * 2], bf[kc], acc, 0, 0, 0);
#pragma unroll
        for (int r = 0; r < 16; ++r) {
            int row = r0 + (r & 3) + 8 * (r >> 2) + 4 * q;
            float v = fmaxf(acc[r] + bc, 0.0f) * norm[row];
            out[(size_t)row * D + col] = __float2half_rn(v);
        }
    }
}

// ---------------- MFMA GEMM2: colsum_j = sum_i relu(H@W2 + b2)_ij ------------
__global__ __launch_bounds__(256) void gemm2_mfma_colsum(const __half* __restrict__ H,
                                                         const __half* __restrict__ Wt,
                                                         const float* __restrict__ b,
                                                         float* __restrict__ colsum) {
    int lane = threadIdx.x & 63;
    int w = threadIdx.x >> 6;
    int m = lane & 31;
    int q = lane >> 5;
    int col = w * 32 + m;
    half8 bf[8];
    const half8* wp = (const half8*)(Wt + (size_t)col * D + q * 8);
#pragma unroll
    for (int kc = 0; kc < 8; ++kc) bf[kc] = wp[kc * 2];
    float bc = b[col];
    float csum = 0.0f;
    for (int s = blockIdx.x; s < NSTRIP; s += gridDim.x) {
        int r0 = s * 32;
        floatx16 acc;
#pragma unroll
        for (int i = 0; i < 16; ++i) acc[i] = 0.0f;
        const half8* hp = (const half8*)(H + (size_t)(r0 + m) * D + q * 8);
#pragma unroll
        for (int kc = 0; kc < 8; ++kc)
            acc = __builtin_amdgcn_mfma_f32_32x32x16_f16(hp[kc * 2], bf[kc], acc, 0, 0, 0);
#pragma unroll
        for (int r = 0; r < 16; ++r) csum += fmaxf(acc[r] + bc, 0.0f);
    }
    csum += __shfl_down(csum, 32);
    if (lane < 32) atomicAdd(&colsum[col], csum);
}

// ---------------- final tiny MLP + sigmoid ----------------
__global__ __launch_bounds__(128) void final_mlp(const float* __restrict__ colsum,
                                                 const float* __restrict__ Wf1,
                                                 const float* __restrict__ bf1,
                                                 const float* __restrict__ Wf2,
                                                 const float* __restrict__ bf2,
                                                 float* __restrict__ out) {
    __shared__ float hg[D];
    __shared__ float red[D];
    int j = threadIdx.x;
    hg[j] = colsum[j] * (1.0f / (float)NN);
    __syncthreads();
    float acc = bf1[j];
#pragma unroll 16
    for (int k = 0; k < D; ++k)
        acc = fmaf(hg[k], Wf1[k * D + j], acc);
    acc = fmaxf(acc, 0.0f);
    red[j] = acc * Wf2[j];
    __syncthreads();
    for (int s = 64; s > 0; s >>= 1) {
        if (j < s) red[j] += red[j + s];
        __syncthreads();
    }
    if (j == 0) {
        float o = red[0] + bf2[0];
        o = fmaxf(o, 0.0f);
        out[0] = 1.0f / (1.0f + expf(-o));
    }
}

// ---------------- launch ------------------------------------------------------
extern "C" void kernel_launch(void* const* d_in, const int* in_sizes, int n_in,
                              void* d_out, int out_size, void* d_ws, size_t ws_size,
                              hipStream_t stream) {
    const float* x   = (const float*)d_in[0];
    const int*   src = (const int*)d_in[1];
    const int*   dst = (const int*)d_in[2];
    const float* W1  = (const float*)d_in[3];
    const float* b1  = (const float*)d_in[4];
    const float* W2  = (const float*)d_in[5];
    const float* b2  = (const float*)d_in[6];
    const float* Wf1 = (const float*)d_in[7];
    const float* bf1 = (const float*)d_in[8];
    const float* Wf2 = (const float*)d_in[9];
    const float* bf2 = (const float*)d_in[10];
    float* out = (float*)d_out;

    char* ws = (char*)d_ws;
    constexpr size_t OFF_CC   = 0;
    constexpr size_t OFF_CO   = 4096;
    constexpr size_t OFF_CU   = 8192;
    constexpr size_t OFF_CS   = 12288;                          // colsum (512 B)
    constexpr size_t OFF_WT1  = 16384;                          // 32 KB
    constexpr size_t OFF_WT2  = OFF_WT1 + 32768;
    constexpr size_t OFF_RP   = OFF_WT2 + 32768;                // NN+1 ints
    constexpr size_t OFF_NORM = OFF_RP + 400128;
    constexpr size_t OFF_EBUF = OFF_NORM + 400128;              // EE int2
    constexpr size_t OFF_CSR  = OFF_EBUF + (size_t)EE * 8;
    constexpr size_t OFF_A    = OFF_CSR + (size_t)EE * 4;
    constexpr size_t OFF_B    = OFF_A + (size_t)NN * D * 2;
    int*    ccnt   = (int*)(ws + OFF_CC);
    int*    coff   = (int*)(ws + OFF_CO);
    int*    ccur   = (int*)(ws + OFF_CU);
    float*  colsum = (float*)(ws + OFF_CS);
    __half* Wt1    = (__half*)(ws + OFF_WT1);
    __half* Wt2    = (__half*)(ws + OFF_WT2);
    int*    rowptr = (int*)(ws + OFF_RP);
    float*  norm   = (float*)(ws + OFF_NORM);
    int2*   ebuf   = (int2*)(ws + OFF_EBUF);
    int*    csr    = (int*)(ws + OFF_CSR);
    __half* bufA   = (__half*)(ws + OFF_A);
    __half* bufB   = (__half*)(ws + OFF_B);

    const int nT = 256;
    const int gridC = (NN * 64 + nT - 1) / nT;
    const int gridG = NN / 16;   // 6250 blocks, 16 nodes/block, 16 lanes/node

    // ---- CSR build + norm ----
    hipMemsetAsync(ccnt, 0, (size_t)NB * 4, stream);
    coarse_count<<<NBLK, 256, 0, stream>>>(dst, ccnt);
    coarse_scan<<<1, 512, 0, stream>>>(ccnt, coff, ccur);
    coarse_scatter<<<NBLK, 256, 0, stream>>>(src, dst, ccur, ebuf);
    fine_sort<<<NB, 256, 0, stream>>>(ebuf, coff, rowptr, norm, csr);

    // ---- weight prep (fp16 transposed) ----
    conv_w<<<64, 256, 0, stream>>>(W1, Wt1);
    conv_w<<<64, 256, 0, stream>>>(W2, Wt2);

    // ---- propagation block 1 ----
    convert_scale<<<gridC, nT, 0, stream>>>((const float2*)x, (__half2*)bufA, norm);
    gather_half<0><<<gridG, 256, 0, stream>>>(rowptr, csr, bufA, norm, bufB);
    gather_half<0><<<gridG, 256, 0, stream>>>(rowptr, csr, bufB, norm, bufA);
    gather_half<1><<<gridG, 256, 0, stream>>>(rowptr, csr, bufA, norm, bufB);

    // ---- g = fp16(relu(h @ W1 + b1) * norm) : bufB -> bufA (MFMA) ----
    gemm1_mfma<<<625, 256, 0, stream>>>(bufB, Wt1, b1, norm, bufA);

    // ---- propagation block 2 ----
    gather_half<0><<<gridG, 256, 0, stream>>>(rowptr, csr, bufA, norm, bufB);
    gather_half<0><<<gridG, 256, 0, stream>>>(rowptr, csr, bufB, norm, bufA);
    gather_half<1><<<gridG, 256, 0, stream>>>(rowptr, csr, bufA, norm, bufB);

    // ---- colsum of relu(h @ W2 + b2) (MFMA) ----
    hipMemsetAsync(colsum, 0, D * 4, stream);
    gemm2_mfma_colsum<<<250, 256, 0, stream>>>(bufB, Wt2, b2, colsum);

    // ---- final MLP + sigmoid ----
    final_mlp<<<1, 128, 0, stream>>>(colsum, Wf1, bf1, Wf2, bf2, out);
}

// Round 6
// 713.307 us; speedup vs baseline: 46.6108x; 1.3275x over previous
//
#include <hip/hip_runtime.h>
#include <hip/hip_fp16.h>
#include <math.h>

#define NN 100000
#define EE 3200000
#define D 128
#define NB 391        // coarse buckets: node>>8
#define NBLK 256
#define ECHUNK ((EE + NBLK - 1) / NBLK)
#define NSTRIP (NN / 32)

#define SCALE_R 6.0f      // per-round rescale to keep fp8 values ~O(0.3)
#define SCALE_G 512.0f    // post-GEMM1 rescale

typedef _Float16 half8 __attribute__((ext_vector_type(8)));
typedef float floatx16 __attribute__((ext_vector_type(16)));
typedef float v2f __attribute__((ext_vector_type(2)));

// ---------------- CSR build (unchanged from R5) ----------------
__global__ __launch_bounds__(256) void coarse_count(const int* __restrict__ dst,
                                                    int* __restrict__ coarse_cnt) {
    __shared__ int hist[NB];
    for (int i = threadIdx.x; i < NB; i += 256) hist[i] = 0;
    __syncthreads();
    int e0 = blockIdx.x * ECHUNK;
    int e1 = e0 + ECHUNK; if (e1 > EE) e1 = EE;
    for (int e = e0 + threadIdx.x; e < e1; e += 256)
        atomicAdd(&hist[dst[e] >> 8], 1);
    __syncthreads();
    for (int i = threadIdx.x; i < NB; i += 256)
        if (hist[i]) atomicAdd(&coarse_cnt[i], hist[i]);
}

__global__ __launch_bounds__(512) void coarse_scan(const int* __restrict__ coarse_cnt,
                                                   int* __restrict__ coarse_off,
                                                   int* __restrict__ coarse_cursor) {
    __shared__ int s[512];
    int t = threadIdx.x;
    int v = (t < NB) ? coarse_cnt[t] : 0;
    s[t] = v;
    __syncthreads();
    for (int off = 1; off < 512; off <<= 1) {
        int x = (t >= off) ? s[t - off] : 0;
        __syncthreads();
        s[t] += x;
        __syncthreads();
    }
    int excl = s[t] - v;
    if (t < NB) { coarse_off[t] = excl; coarse_cursor[t] = excl; }
    if (t == NB) coarse_off[NB] = excl;
}

__global__ __launch_bounds__(256) void coarse_scatter(const int* __restrict__ src,
                                                      const int* __restrict__ dst,
                                                      int* __restrict__ coarse_cursor,
                                                      int2* __restrict__ ebuf) {
    __shared__ int hist[NB];
    __shared__ int base[NB];
    for (int i = threadIdx.x; i < NB; i += 256) hist[i] = 0;
    __syncthreads();
    int e0 = blockIdx.x * ECHUNK;
    int e1 = e0 + ECHUNK; if (e1 > EE) e1 = EE;
    for (int e = e0 + threadIdx.x; e < e1; e += 256)
        atomicAdd(&hist[dst[e] >> 8], 1);
    __syncthreads();
    for (int i = threadIdx.x; i < NB; i += 256) {
        int c = hist[i];
        base[i] = c ? atomicAdd(&coarse_cursor[i], c) : 0;
    }
    __syncthreads();
    for (int e = e0 + threadIdx.x; e < e1; e += 256) {
        int d = dst[e];
        int pos = atomicAdd(&base[d >> 8], 1);
        ebuf[pos] = make_int2(src[e], d);
    }
}

__global__ __launch_bounds__(256) void fine_sort(const int2* __restrict__ ebuf,
                                                 const int* __restrict__ coarse_off,
                                                 int* __restrict__ rowptr,
                                                 float* __restrict__ norm,
                                                 int* __restrict__ csr) {
    __shared__ int cnt[256];
    __shared__ int sbuf[256];
    int b = blockIdx.x;
    int t = threadIdx.x;
    int e0 = coarse_off[b], e1 = coarse_off[b + 1];
    int n0 = b << 8;
    cnt[t] = 0;
    __syncthreads();
    for (int e = e0 + t; e < e1; e += 256)
        atomicAdd(&cnt[ebuf[e].y & 255], 1);
    __syncthreads();
    int myc = cnt[t];
    sbuf[t] = myc;
    __syncthreads();
    for (int off = 1; off < 256; off <<= 1) {
        int x = (t >= off) ? sbuf[t - off] : 0;
        __syncthreads();
        sbuf[t] += x;
        __syncthreads();
    }
    int excl = sbuf[t] - myc;
    int node = n0 + t;
    if (node < NN) {
        rowptr[node] = e0 + excl;
        float dd = (float)myc;
        if (dd < 1.0f) dd = 1.0f;
        norm[node] = rsqrtf(dd);
    }
    cnt[t] = e0 + excl;
    __syncthreads();
    for (int e = e0 + t; e < e1; e += 256) {
        int2 p = ebuf[e];
        int pos = atomicAdd(&cnt[p.y & 255], 1);
        csr[pos] = p.x;
    }
    if (b == 0 && t == 0) rowptr[NN] = EE;
}

// ---------------- weight convert + transpose: Wt[n*D+k] = fp16(W[k*D+n]) ------
__global__ void conv_w(const float* __restrict__ W, __half* __restrict__ Wt) {
    int idx = blockIdx.x * 256 + threadIdx.x;
    if (idx < D * D) {
        int n = idx >> 7, k = idx & 127;
        Wt[idx] = __float2half_rn(W[k * D + n]);
    }
}

// ---------------- convert+scale: g0 = fp8(x * norm) ----------------
__global__ void convert_scale_fp8(const float4* __restrict__ x4, int* __restrict__ g,
                                  const float* __restrict__ norm) {
    int idx = blockIdx.x * 256 + threadIdx.x;   // NN*32 threads, 4 cols each
    if (idx < NN * 32) {
        int row = idx >> 5;
        float n = norm[row];
        float4 v = x4[idx];
        int w = __builtin_amdgcn_cvt_pk_fp8_f32(v.x * n, v.y * n, 0, 0);
        w = __builtin_amdgcn_cvt_pk_fp8_f32(v.z * n, v.w * n, w, 1);
        g[idx] = w;
    }
}

// ---------------- CSR gather on fp8 rows ----------------
// One wave per node. lane = e*8 + c: 8 parallel edges x 8 col-chunks(16 fp8 = int4).
// mult = OUT16 ? n*post : n*n*post.  OUT16 writes fp16 rows, else fp8 rows.
template <int OUT16>
__global__ __launch_bounds__(256) void gather_fp8(const int* __restrict__ rowptr,
                                                  const int* __restrict__ csr,
                                                  const int4* __restrict__ hs,  // 8 int4 per row
                                                  const float* __restrict__ norm,
                                                  void* __restrict__ outv, float post) {
    int node = blockIdx.x * 4 + (threadIdx.x >> 6);
    int lane = threadIdx.x & 63;
    int e = lane >> 3;
    int c = lane & 7;
    int p0 = rowptr[node], p1 = rowptr[node + 1];
    float acc[16];
#pragma unroll
    for (int i = 0; i < 16; ++i) acc[i] = 0.0f;
    for (int p = p0 + e; p < p1; p += 8) {
        int s = csr[p];
        int4 v = hs[(size_t)s * 8 + c];
        v2f f;
        f = __builtin_amdgcn_cvt_pk_f32_fp8(v.x, 0); acc[0] += f.x;  acc[1] += f.y;
        f = __builtin_amdgcn_cvt_pk_f32_fp8(v.x, 1); acc[2] += f.x;  acc[3] += f.y;
        f = __builtin_amdgcn_cvt_pk_f32_fp8(v.y, 0); acc[4] += f.x;  acc[5] += f.y;
        f = __builtin_amdgcn_cvt_pk_f32_fp8(v.y, 1); acc[6] += f.x;  acc[7] += f.y;
        f = __builtin_amdgcn_cvt_pk_f32_fp8(v.z, 0); acc[8] += f.x;  acc[9] += f.y;
        f = __builtin_amdgcn_cvt_pk_f32_fp8(v.z, 1); acc[10] += f.x; acc[11] += f.y;
        f = __builtin_amdgcn_cvt_pk_f32_fp8(v.w, 0); acc[12] += f.x; acc[13] += f.y;
        f = __builtin_amdgcn_cvt_pk_f32_fp8(v.w, 1); acc[14] += f.x; acc[15] += f.y;
    }
#pragma unroll
    for (int off = 8; off < 64; off <<= 1) {
#pragma unroll
        for (int i = 0; i < 16; ++i) acc[i] += __shfl_xor(acc[i], off, 64);
    }
    if (e == 0) {
        float n = norm[node];
        float m = (OUT16 ? n : n * n) * post;
#pragma unroll
        for (int i = 0; i < 16; ++i) acc[i] *= m;
        if (OUT16) {
            union { int4 q; __half2 h[4]; } u0, u1;
#pragma unroll
            for (int i = 0; i < 4; ++i) {
                u0.h[i] = __floats2half2_rn(acc[2 * i], acc[2 * i + 1]);
                u1.h[i] = __floats2half2_rn(acc[8 + 2 * i], acc[9 + 2 * i]);
            }
            int4* o = (int4*)((__half*)outv + (size_t)node * D + c * 16);
            o[0] = u0.q;
            o[1] = u1.q;
        } else {
            int4 w;
            w.x = __builtin_amdgcn_cvt_pk_fp8_f32(acc[0], acc[1], 0, 0);
            w.x = __builtin_amdgcn_cvt_pk_fp8_f32(acc[2], acc[3], w.x, 1);
            w.y = __builtin_amdgcn_cvt_pk_fp8_f32(acc[4], acc[5], 0, 0);
            w.y = __builtin_amdgcn_cvt_pk_fp8_f32(acc[6], acc[7], w.y, 1);
            w.z = __builtin_amdgcn_cvt_pk_fp8_f32(acc[8], acc[9], 0, 0);
            w.z = __builtin_amdgcn_cvt_pk_fp8_f32(acc[10], acc[11], w.z, 1);
            w.w = __builtin_amdgcn_cvt_pk_fp8_f32(acc[12], acc[13], 0, 0);
            w.w = __builtin_amdgcn_cvt_pk_fp8_f32(acc[14], acc[15], w.w, 1);
            ((int4*)outv)[(size_t)node * 8 + c] = w;
        }
    }
}

// ---------------- MFMA GEMM1: out_fp8 = fp8(relu(H@W1 + b1) * norm * SCALE_G) -
__global__ __launch_bounds__(256) void gemm1_mfma(const __half* __restrict__ H,
                                                  const __half* __restrict__ Wt,
                                                  const float* __restrict__ b,
                                                  const float* __restrict__ norm,
                                                  char* __restrict__ out8) {
    int lane = threadIdx.x & 63;
    int w = threadIdx.x >> 6;
    int m = lane & 31;
    int q = lane >> 5;
    int col = w * 32 + m;
    half8 bf[8];
    const half8* wp = (const half8*)(Wt + (size_t)col * D + q * 8);
#pragma unroll
    for (int kc = 0; kc < 8; ++kc) bf[kc] = wp[kc * 2];
    float bc = b[col];
    for (int s = blockIdx.x; s < NSTRIP; s += gridDim.x) {
        int r0 = s * 32;
        floatx16 acc;
#pragma unroll
        for (int i = 0; i < 16; ++i) acc[i] = 0.0f;
        const half8* hp = (const half8*)(H + (size_t)(r0 + m) * D + q * 8);
#pragma unroll
        for (int kc = 0; kc < 8; ++kc)
            acc = __builtin_amdgcn_mfma_f32_32x32x16_f16(hp[kc * 2], bf[kc], acc, 0, 0, 0);
#pragma unroll
        for (int r = 0; r < 16; ++r) {
            int row = r0 + (r & 3) + 8 * (r >> 2) + 4 * q;
            float v = fmaxf(acc[r] + bc, 0.0f) * norm[row] * SCALE_G;
            int pk = __builtin_amdgcn_cvt_pk_fp8_f32(v, v, 0, 0);
            out8[(size_t)row * D + col] = (char)(pk & 0xff);
        }
    }
}

// ---------------- MFMA GEMM2: colsum_j = sum_i relu(H@W2 + b2)_ij ------------
__global__ __launch_bounds__(256) void gemm2_mfma_colsum(const __half* __restrict__ H,
                                                         const __half* __restrict__ Wt,
                                                         const float* __restrict__ b,
                                                         float* __restrict__ colsum) {
    int lane = threadIdx.x & 63;
    int w = threadIdx.x >> 6;
    int m = lane & 31;
    int q = lane >> 5;
    int col = w * 32 + m;
    half8 bf[8];
    const half8* wp = (const half8*)(Wt + (size_t)col * D + q * 8);
#pragma unroll
    for (int kc = 0; kc < 8; ++kc) bf[kc] = wp[kc * 2];
    float bc = b[col];
    float csum = 0.0f;
    for (int s = blockIdx.x; s < NSTRIP; s += gridDim.x) {
        int r0 = s * 32;
        floatx16 acc;
#pragma unroll
        for (int i = 0; i < 16; ++i) acc[i] = 0.0f;
        const half8* hp = (const half8*)(H + (size_t)(r0 + m) * D + q * 8);
#pragma unroll
        for (int kc = 0; kc < 8; ++kc)
            acc = __builtin_amdgcn_mfma_f32_32x32x16_f16(hp[kc * 2], bf[kc], acc, 0, 0, 0);
#pragma unroll
        for (int r = 0; r < 16; ++r) csum += fmaxf(acc[r] + bc, 0.0f);
    }
    csum += __shfl_down(csum, 32);
    if (lane < 32) atomicAdd(&colsum[col], csum);
}

// ---------------- final tiny MLP + sigmoid ----------------
__global__ __launch_bounds__(128) void final_mlp(const float* __restrict__ colsum,
                                                 const float* __restrict__ Wf1,
                                                 const float* __restrict__ bf1,
                                                 const float* __restrict__ Wf2,
                                                 const float* __restrict__ bf2,
                                                 float* __restrict__ out) {
    __shared__ float hg[D];
    __shared__ float red[D];
    int j = threadIdx.x;
    hg[j] = colsum[j] * (1.0f / (float)NN);
    __syncthreads();
    float acc = bf1[j];
#pragma unroll 16
    for (int k = 0; k < D; ++k)
        acc = fmaf(hg[k], Wf1[k * D + j], acc);
    acc = fmaxf(acc, 0.0f);
    red[j] = acc * Wf2[j];
    __syncthreads();
    for (int s = 64; s > 0; s >>= 1) {
        if (j < s) red[j] += red[j + s];
        __syncthreads();
    }
    if (j == 0) {
        float o = red[0] + bf2[0];
        o = fmaxf(o, 0.0f);
        out[0] = 1.0f / (1.0f + expf(-o));
    }
}

// ---------------- launch ------------------------------------------------------
extern "C" void kernel_launch(void* const* d_in, const int* in_sizes, int n_in,
                              void* d_out, int out_size, void* d_ws, size_t ws_size,
                              hipStream_t stream) {
    const float* x   = (const float*)d_in[0];
    const int*   src = (const int*)d_in[1];
    const int*   dst = (const int*)d_in[2];
    const float* W1  = (const float*)d_in[3];
    const float* b1  = (const float*)d_in[4];
    const float* W2  = (const float*)d_in[5];
    const float* b2  = (const float*)d_in[6];
    const float* Wf1 = (const float*)d_in[7];
    const float* bf1 = (const float*)d_in[8];
    const float* Wf2 = (const float*)d_in[9];
    const float* bf2 = (const float*)d_in[10];
    float* out = (float*)d_out;

    char* ws = (char*)d_ws;
    constexpr size_t OFF_CC   = 0;
    constexpr size_t OFF_CO   = 4096;
    constexpr size_t OFF_CU   = 8192;
    constexpr size_t OFF_CS   = 12288;                          // colsum
    constexpr size_t OFF_WT1  = 16384;                          // 32 KB fp16
    constexpr size_t OFF_WT2  = OFF_WT1 + 32768;
    constexpr size_t OFF_RP   = OFF_WT2 + 32768;                // NN+1 ints
    constexpr size_t OFF_NORM = OFF_RP + 400128;
    constexpr size_t OFF_EBUF = OFF_NORM + 400128;              // EE int2 (25.6 MB)
    constexpr size_t OFF_CSR  = OFF_EBUF + (size_t)EE * 8;      // EE ints (12.8 MB)
    constexpr size_t OFF_A8   = OFF_CSR + (size_t)EE * 4;       // NN*D fp8 (12.8 MB)
    constexpr size_t OFF_B8   = OFF_A8 + (size_t)NN * D;        // NN*D fp8
    constexpr size_t OFF_H16  = OFF_B8 + (size_t)NN * D;        // NN*D fp16 (25.6 MB)
    int*    ccnt   = (int*)(ws + OFF_CC);
    int*    coff   = (int*)(ws + OFF_CO);
    int*    ccur   = (int*)(ws + OFF_CU);
    float*  colsum = (float*)(ws + OFF_CS);
    __half* Wt1    = (__half*)(ws + OFF_WT1);
    __half* Wt2    = (__half*)(ws + OFF_WT2);
    int*    rowptr = (int*)(ws + OFF_RP);
    float*  norm   = (float*)(ws + OFF_NORM);
    int2*   ebuf   = (int2*)(ws + OFF_EBUF);
    int*    csr    = (int*)(ws + OFF_CSR);
    char*   bufA8  = ws + OFF_A8;
    char*   bufB8  = ws + OFF_B8;
    __half* bufH   = (__half*)(ws + OFF_H16);

    const int nT = 256;
    const int gridC = (NN * 32 + nT - 1) / nT;
    const int gridG = NN / 4;   // one wave per node, 4 waves/block

    const float invR2  = 1.0f / (SCALE_R * SCALE_R);
    const float invGR2 = 1.0f / (SCALE_G * SCALE_R * SCALE_R);

    // ---- CSR build + norm ----
    hipMemsetAsync(ccnt, 0, (size_t)NB * 4, stream);
    coarse_count<<<NBLK, 256, 0, stream>>>(dst, ccnt);
    coarse_scan<<<1, 512, 0, stream>>>(ccnt, coff, ccur);
    coarse_scatter<<<NBLK, 256, 0, stream>>>(src, dst, ccur, ebuf);
    fine_sort<<<NB, 256, 0, stream>>>(ebuf, coff, rowptr, norm, csr);

    // ---- weight prep ----
    conv_w<<<64, 256, 0, stream>>>(W1, Wt1);
    conv_w<<<64, 256, 0, stream>>>(W2, Wt2);

    // ---- propagation block 1 (fp8 rows, rescaled) ----
    convert_scale_fp8<<<gridC, nT, 0, stream>>>((const float4*)x, (int*)bufA8, norm);
    gather_fp8<0><<<gridG, 256, 0, stream>>>(rowptr, csr, (const int4*)bufA8, norm, bufB8, SCALE_R);
    gather_fp8<0><<<gridG, 256, 0, stream>>>(rowptr, csr, (const int4*)bufB8, norm, bufA8, SCALE_R);
    gather_fp8<1><<<gridG, 256, 0, stream>>>(rowptr, csr, (const int4*)bufA8, norm, bufH, invR2);

    // ---- g = fp8(relu(h @ W1 + b1) * norm * SCALE_G) ----
    gemm1_mfma<<<625, 256, 0, stream>>>(bufH, Wt1, b1, norm, bufA8);

    // ---- propagation block 2 ----
    gather_fp8<0><<<gridG, 256, 0, stream>>>(rowptr, csr, (const int4*)bufA8, norm, bufB8, SCALE_R);
    gather_fp8<0><<<gridG, 256, 0, stream>>>(rowptr, csr, (const int4*)bufB8, norm, bufA8, SCALE_R);
    gather_fp8<1><<<gridG, 256, 0, stream>>>(rowptr, csr, (const int4*)bufA8, norm, bufH, invGR2);

    // ---- colsum of relu(h @ W2 + b2) ----
    hipMemsetAsync(colsum, 0, D * 4, stream);
    gemm2_mfma_colsum<<<250, 256, 0, stream>>>(bufH, Wt2, b2, colsum);

    // ---- final MLP + sigmoid ----
    final_mlp<<<1, 128, 0, stream>>>(colsum, Wf1, bf1, Wf2, bf2, out);
}

// Round 7
// 680.385 us; speedup vs baseline: 48.8662x; 1.0484x over previous
//
#include <hip/hip_runtime.h>
#include <hip/hip_fp16.h>
#include <math.h>

#define NN 100000
#define EE 3200000
#define D 128
#define NB 391        // coarse buckets: node>>8
#define NBLK2 1024    // blocks for hist/scatter passes
#define ECH2 (EE / NBLK2)   // 3125 edges per block (exact)
#define NSTRIP (NN / 32)

#define SCALE_R 6.0f      // per-round rescale to keep fp8 values ~O(0.3)
#define SCALE_G 512.0f    // post-GEMM1 rescale

typedef _Float16 half8 __attribute__((ext_vector_type(8)));
typedef float floatx16 __attribute__((ext_vector_type(16)));
typedef float v2f __attribute__((ext_vector_type(2)));

// ---------------- build pass 1: per-block histogram (transposed store) --------
__global__ __launch_bounds__(256) void block_hist(const int* __restrict__ dst,
                                                  int* __restrict__ bh) {
    __shared__ int hist[NB];
    for (int i = threadIdx.x; i < NB; i += 256) hist[i] = 0;
    __syncthreads();
    int e0 = blockIdx.x * ECH2;
    for (int e = e0 + threadIdx.x; e < e0 + ECH2; e += 256)
        atomicAdd(&hist[dst[e] >> 8], 1);
    __syncthreads();
    for (int i = threadIdx.x; i < NB; i += 256)
        bh[i * NBLK2 + blockIdx.x] = hist[i];
}

// ---------------- build pass 2: per-bin exclusive scan over blocks ------------
__global__ __launch_bounds__(256) void bin_scan(int* __restrict__ bh,
                                                int* __restrict__ bintot) {
    __shared__ int ts[256];
    int i = blockIdx.x;
    int t = threadIdx.x;
    int4 v = ((int4*)(bh + i * NBLK2))[t];
    int s = v.x + v.y + v.z + v.w;
    ts[t] = s;
    __syncthreads();
    for (int off = 1; off < 256; off <<= 1) {
        int x = (t >= off) ? ts[t - off] : 0;
        __syncthreads();
        ts[t] += x;
        __syncthreads();
    }
    int run = ts[t] - s;
    int4 o;
    o.x = run; o.y = run + v.x; o.z = o.y + v.y; o.w = o.z + v.z;
    ((int4*)(bh + i * NBLK2))[t] = o;
    if (t == 255) bintot[i] = ts[255];
}

// ---------------- build pass 3: exclusive scan of bin totals -> coff ----------
__global__ __launch_bounds__(512) void tiny_scan(const int* __restrict__ bintot,
                                                 int* __restrict__ coff) {
    __shared__ int s[512];
    int t = threadIdx.x;
    int v = (t < NB) ? bintot[t] : 0;
    s[t] = v;
    __syncthreads();
    for (int off = 1; off < 512; off <<= 1) {
        int x = (t >= off) ? s[t - off] : 0;
        __syncthreads();
        s[t] += x;
        __syncthreads();
    }
    int excl = s[t] - v;
    if (t <= NB) coff[t] = excl;   // coff[NB] == EE
}

// ---------------- build pass 4: scatter with precomputed bases ----------------
__global__ __launch_bounds__(256) void scatter2(const int* __restrict__ src,
                                                const int* __restrict__ dst,
                                                const int* __restrict__ bh,
                                                const int* __restrict__ coff,
                                                int2* __restrict__ ebuf) {
    __shared__ int base[NB];
    int b = blockIdx.x;
    for (int i = threadIdx.x; i < NB; i += 256)
        base[i] = coff[i] + bh[i * NBLK2 + b];
    __syncthreads();
    int e0 = b * ECH2;
    for (int e = e0 + threadIdx.x; e < e0 + ECH2; e += 256) {
        int d = dst[e];
        int pos = atomicAdd(&base[d >> 8], 1);
        ebuf[pos] = make_int2(src[e], d);
    }
}

// ---------------- build pass 5: per-bucket fine sort -> rowptr/norm/csr -------
__global__ __launch_bounds__(256) void fine_sort(const int2* __restrict__ ebuf,
                                                 const int* __restrict__ coarse_off,
                                                 int* __restrict__ rowptr,
                                                 float* __restrict__ norm,
                                                 int* __restrict__ csr) {
    __shared__ int cnt[256];
    __shared__ int sbuf[256];
    int b = blockIdx.x;
    int t = threadIdx.x;
    int e0 = coarse_off[b], e1 = coarse_off[b + 1];
    int n0 = b << 8;
    cnt[t] = 0;
    __syncthreads();
    for (int e = e0 + t; e < e1; e += 256)
        atomicAdd(&cnt[ebuf[e].y & 255], 1);
    __syncthreads();
    int myc = cnt[t];
    sbuf[t] = myc;
    __syncthreads();
    for (int off = 1; off < 256; off <<= 1) {
        int x = (t >= off) ? sbuf[t - off] : 0;
        __syncthreads();
        sbuf[t] += x;
        __syncthreads();
    }
    int excl = sbuf[t] - myc;
    int node = n0 + t;
    if (node < NN) {
        rowptr[node] = e0 + excl;
        float dd = (float)myc;
        if (dd < 1.0f) dd = 1.0f;
        norm[node] = rsqrtf(dd);
    }
    cnt[t] = e0 + excl;
    __syncthreads();
    for (int e = e0 + t; e < e1; e += 256) {
        int2 p = ebuf[e];
        int pos = atomicAdd(&cnt[p.y & 255], 1);
        csr[pos] = p.x;
    }
    if (b == 0 && t == 0) rowptr[NN] = EE;
}

// ---------------- weight convert + transpose: Wt[n*D+k] = fp16(W[k*D+n]) ------
__global__ void conv_w(const float* __restrict__ W, __half* __restrict__ Wt) {
    int idx = blockIdx.x * 256 + threadIdx.x;
    if (idx < D * D) {
        int n = idx >> 7, k = idx & 127;
        Wt[idx] = __float2half_rn(W[k * D + n]);
    }
}

// ---------------- convert+scale: g0 = fp8(x * norm) ----------------
__global__ void convert_scale_fp8(const float4* __restrict__ x4, int* __restrict__ g,
                                  const float* __restrict__ norm) {
    int idx = blockIdx.x * 256 + threadIdx.x;   // NN*32 threads, 4 cols each
    if (idx < NN * 32) {
        int row = idx >> 5;
        float n = norm[row];
        float4 v = x4[idx];
        int w = __builtin_amdgcn_cvt_pk_fp8_f32(v.x * n, v.y * n, 0, 0);
        w = __builtin_amdgcn_cvt_pk_fp8_f32(v.z * n, v.w * n, w, 1);
        g[idx] = w;
    }
}

// ---------------- CSR gather on fp8 rows ----------------
// One wave per node. lane = e*8 + c: 8 parallel edges x 8 col-chunks(16 fp8 = int4).
template <int OUT16>
__global__ __launch_bounds__(256) void gather_fp8(const int* __restrict__ rowptr,
                                                  const int* __restrict__ csr,
                                                  const int4* __restrict__ hs,  // 8 int4 per row
                                                  const float* __restrict__ norm,
                                                  void* __restrict__ outv, float post) {
    int node = blockIdx.x * 4 + (threadIdx.x >> 6);
    int lane = threadIdx.x & 63;
    int e = lane >> 3;
    int c = lane & 7;
    int p0 = rowptr[node], p1 = rowptr[node + 1];
    float acc[16];
#pragma unroll
    for (int i = 0; i < 16; ++i) acc[i] = 0.0f;
    for (int p = p0 + e; p < p1; p += 8) {
        int s = csr[p];
        int4 v = hs[(size_t)s * 8 + c];
        v2f f;
        f = __builtin_amdgcn_cvt_pk_f32_fp8(v.x, 0); acc[0] += f.x;  acc[1] += f.y;
        f = __builtin_amdgcn_cvt_pk_f32_fp8(v.x, 1); acc[2] += f.x;  acc[3] += f.y;
        f = __builtin_amdgcn_cvt_pk_f32_fp8(v.y, 0); acc[4] += f.x;  acc[5] += f.y;
        f = __builtin_amdgcn_cvt_pk_f32_fp8(v.y, 1); acc[6] += f.x;  acc[7] += f.y;
        f = __builtin_amdgcn_cvt_pk_f32_fp8(v.z, 0); acc[8] += f.x;  acc[9] += f.y;
        f = __builtin_amdgcn_cvt_pk_f32_fp8(v.z, 1); acc[10] += f.x; acc[11] += f.y;
        f = __builtin_amdgcn_cvt_pk_f32_fp8(v.w, 0); acc[12] += f.x; acc[13] += f.y;
        f = __builtin_amdgcn_cvt_pk_f32_fp8(v.w, 1); acc[14] += f.x; acc[15] += f.y;
    }
#pragma unroll
    for (int off = 8; off < 64; off <<= 1) {
#pragma unroll
        for (int i = 0; i < 16; ++i) acc[i] += __shfl_xor(acc[i], off, 64);
    }
    if (e == 0) {
        float n = norm[node];
        float m = (OUT16 ? n : n * n) * post;
#pragma unroll
        for (int i = 0; i < 16; ++i) acc[i] *= m;
        if (OUT16) {
            union { int4 q; __half2 h[4]; } u0, u1;
#pragma unroll
            for (int i = 0; i < 4; ++i) {
                u0.h[i] = __floats2half2_rn(acc[2 * i], acc[2 * i + 1]);
                u1.h[i] = __floats2half2_rn(acc[8 + 2 * i], acc[9 + 2 * i]);
            }
            int4* o = (int4*)((__half*)outv + (size_t)node * D + c * 16);
            o[0] = u0.q;
            o[1] = u1.q;
        } else {
            int4 w;
            w.x = __builtin_amdgcn_cvt_pk_fp8_f32(acc[0], acc[1], 0, 0);
            w.x = __builtin_amdgcn_cvt_pk_fp8_f32(acc[2], acc[3], w.x, 1);
            w.y = __builtin_amdgcn_cvt_pk_fp8_f32(acc[4], acc[5], 0, 0);
            w.y = __builtin_amdgcn_cvt_pk_fp8_f32(acc[6], acc[7], w.y, 1);
            w.z = __builtin_amdgcn_cvt_pk_fp8_f32(acc[8], acc[9], 0, 0);
            w.z = __builtin_amdgcn_cvt_pk_fp8_f32(acc[10], acc[11], w.z, 1);
            w.w = __builtin_amdgcn_cvt_pk_fp8_f32(acc[12], acc[13], 0, 0);
            w.w = __builtin_amdgcn_cvt_pk_fp8_f32(acc[14], acc[15], w.w, 1);
            ((int4*)outv)[(size_t)node * 8 + c] = w;
        }
    }
}

// ---------------- MFMA GEMM1: out_fp8 = fp8(relu(H@W1 + b1) * norm * SCALE_G) -
__global__ __launch_bounds__(256) void gemm1_mfma(const __half* __restrict__ H,
                                                  const __half* __restrict__ Wt,
                                                  const float* __restrict__ b,
                                                  const float* __restrict__ norm,
                                                  char* __restrict__ out8) {
    int lane = threadIdx.x & 63;
    int w = threadIdx.x >> 6;
    int m = lane & 31;
    int q = lane >> 5;
    int col = w * 32 + m;
    half8 bf[8];
    const half8* wp = (const half8*)(Wt + (size_t)col * D + q * 8);
#pragma unroll
    for (int kc = 0; kc < 8; ++kc) bf[kc] = wp[kc * 2];
    float bc = b[col];
    for (int s = blockIdx.x; s < NSTRIP; s += gridDim.x) {
        int r0 = s * 32;
        floatx16 acc;
#pragma unroll
        for (int i = 0; i < 16; ++i) acc[i] = 0.0f;
        const half8* hp = (const half8*)(H + (size_t)(r0 + m) * D + q * 8);
#pragma unroll
        for (int kc = 0; kc < 8; ++kc)
            acc = __builtin_amdgcn_mfma_f32_32x32x16_f16(hp[kc * 2], bf[kc], acc, 0, 0, 0);
#pragma unroll
        for (int r = 0; r < 16; ++r) {
            int row = r0 + (r & 3) + 8 * (r >> 2) + 4 * q;
            float v = fmaxf(acc[r] + bc, 0.0f) * norm[row] * SCALE_G;
            int pk = __builtin_amdgcn_cvt_pk_fp8_f32(v, v, 0, 0);
            out8[(size_t)row * D + col] = (char)(pk & 0xff);
        }
    }
}

// ---------------- MFMA GEMM2: colsum_j = sum_i relu(H@W2 + b2)_ij ------------
__global__ __launch_bounds__(256) void gemm2_mfma_colsum(const __half* __restrict__ H,
                                                         const __half* __restrict__ Wt,
                                                         const float* __restrict__ b,
                                                         float* __restrict__ colsum) {
    int lane = threadIdx.x & 63;
    int w = threadIdx.x >> 6;
    int m = lane & 31;
    int q = lane >> 5;
    int col = w * 32 + m;
    half8 bf[8];
    const half8* wp = (const half8*)(Wt + (size_t)col * D + q * 8);
#pragma unroll
    for (int kc = 0; kc < 8; ++kc) bf[kc] = wp[kc * 2];
    float bc = b[col];
    float csum = 0.0f;
    for (int s = blockIdx.x; s < NSTRIP; s += gridDim.x) {
        int r0 = s * 32;
        floatx16 acc;
#pragma unroll
        for (int i = 0; i < 16; ++i) acc[i] = 0.0f;
        const half8* hp = (const half8*)(H + (size_t)(r0 + m) * D + q * 8);
#pragma unroll
        for (int kc = 0; kc < 8; ++kc)
            acc = __builtin_amdgcn_mfma_f32_32x32x16_f16(hp[kc * 2], bf[kc], acc, 0, 0, 0);
#pragma unroll
        for (int r = 0; r < 16; ++r) csum += fmaxf(acc[r] + bc, 0.0f);
    }
    csum += __shfl_down(csum, 32);
    if (lane < 32) atomicAdd(&colsum[col], csum);
}

// ---------------- final tiny MLP + sigmoid ----------------
__global__ __launch_bounds__(128) void final_mlp(const float* __restrict__ colsum,
                                                 const float* __restrict__ Wf1,
                                                 const float* __restrict__ bf1,
                                                 const float* __restrict__ Wf2,
                                                 const float* __restrict__ bf2,
                                                 float* __restrict__ out) {
    __shared__ float hg[D];
    __shared__ float red[D];
    int j = threadIdx.x;
    hg[j] = colsum[j] * (1.0f / (float)NN);
    __syncthreads();
    float acc = bf1[j];
#pragma unroll 16
    for (int k = 0; k < D; ++k)
        acc = fmaf(hg[k], Wf1[k * D + j], acc);
    acc = fmaxf(acc, 0.0f);
    red[j] = acc * Wf2[j];
    __syncthreads();
    for (int s = 64; s > 0; s >>= 1) {
        if (j < s) red[j] += red[j + s];
        __syncthreads();
    }
    if (j == 0) {
        float o = red[0] + bf2[0];
        o = fmaxf(o, 0.0f);
        out[0] = 1.0f / (1.0f + expf(-o));
    }
}

// ---------------- launch ------------------------------------------------------
extern "C" void kernel_launch(void* const* d_in, const int* in_sizes, int n_in,
                              void* d_out, int out_size, void* d_ws, size_t ws_size,
                              hipStream_t stream) {
    const float* x   = (const float*)d_in[0];
    const int*   src = (const int*)d_in[1];
    const int*   dst = (const int*)d_in[2];
    const float* W1  = (const float*)d_in[3];
    const float* b1  = (const float*)d_in[4];
    const float* W2  = (const float*)d_in[5];
    const float* b2  = (const float*)d_in[6];
    const float* Wf1 = (const float*)d_in[7];
    const float* bf1 = (const float*)d_in[8];
    const float* Wf2 = (const float*)d_in[9];
    const float* bf2 = (const float*)d_in[10];
    float* out = (float*)d_out;

    char* ws = (char*)d_ws;
    constexpr size_t OFF_BT   = 0;                              // NB ints (bin totals)
    constexpr size_t OFF_CO   = 2048;                           // NB+1 ints (coff)
    constexpr size_t OFF_CS   = 4096;                           // colsum (512 B)
    constexpr size_t OFF_WT1  = 8192;                           // 32 KB fp16
    constexpr size_t OFF_WT2  = OFF_WT1 + 32768;
    constexpr size_t OFF_RP   = OFF_WT2 + 32768;                // NN+1 ints
    constexpr size_t OFF_NORM = OFF_RP + 400128;
    constexpr size_t OFF_BH   = OFF_NORM + 400128;              // NB*NBLK2 ints (1.6 MB)
    constexpr size_t OFF_EBUF = OFF_BH + (size_t)NB * NBLK2 * 4;// EE int2 (25.6 MB)
    constexpr size_t OFF_CSR  = OFF_EBUF + (size_t)EE * 8;      // EE ints (12.8 MB)
    constexpr size_t OFF_A8   = OFF_CSR + (size_t)EE * 4;       // NN*D fp8 (12.8 MB)
    constexpr size_t OFF_B8   = OFF_A8 + (size_t)NN * D;        // NN*D fp8
    constexpr size_t OFF_H16  = OFF_B8 + (size_t)NN * D;        // NN*D fp16 (25.6 MB)
    int*    bintot = (int*)(ws + OFF_BT);
    int*    coff   = (int*)(ws + OFF_CO);
    float*  colsum = (float*)(ws + OFF_CS);
    __half* Wt1    = (__half*)(ws + OFF_WT1);
    __half* Wt2    = (__half*)(ws + OFF_WT2);
    int*    rowptr = (int*)(ws + OFF_RP);
    float*  norm   = (float*)(ws + OFF_NORM);
    int*    bh     = (int*)(ws + OFF_BH);
    int2*   ebuf   = (int2*)(ws + OFF_EBUF);
    int*    csr    = (int*)(ws + OFF_CSR);
    char*   bufA8  = ws + OFF_A8;
    char*   bufB8  = ws + OFF_B8;
    __half* bufH   = (__half*)(ws + OFF_H16);

    const int nT = 256;
    const int gridC = (NN * 32 + nT - 1) / nT;
    const int gridG = NN / 4;   // one wave per node, 4 waves/block

    const float invR2  = 1.0f / (SCALE_R * SCALE_R);
    const float invGR2 = 1.0f / (SCALE_G * SCALE_R * SCALE_R);

    // ---- CSR build + norm (no global atomics) ----
    block_hist<<<NBLK2, 256, 0, stream>>>(dst, bh);
    bin_scan<<<NB, 256, 0, stream>>>(bh, bintot);
    tiny_scan<<<1, 512, 0, stream>>>(bintot, coff);
    scatter2<<<NBLK2, 256, 0, stream>>>(src, dst, bh, coff, ebuf);
    fine_sort<<<NB, 256, 0, stream>>>(ebuf, coff, rowptr, norm, csr);

    // ---- weight prep ----
    conv_w<<<64, 256, 0, stream>>>(W1, Wt1);
    conv_w<<<64, 256, 0, stream>>>(W2, Wt2);

    // ---- propagation block 1 (fp8 rows, rescaled) ----
    convert_scale_fp8<<<gridC, nT, 0, stream>>>((const float4*)x, (int*)bufA8, norm);
    gather_fp8<0><<<gridG, 256, 0, stream>>>(rowptr, csr, (const int4*)bufA8, norm, bufB8, SCALE_R);
    gather_fp8<0><<<gridG, 256, 0, stream>>>(rowptr, csr, (const int4*)bufB8, norm, bufA8, SCALE_R);
    gather_fp8<1><<<gridG, 256, 0, stream>>>(rowptr, csr, (const int4*)bufA8, norm, bufH, invR2);

    // ---- g = fp8(relu(h @ W1 + b1) * norm * SCALE_G) ----
    gemm1_mfma<<<625, 256, 0, stream>>>(bufH, Wt1, b1, norm, bufA8);

    // ---- propagation block 2 ----
    gather_fp8<0><<<gridG, 256, 0, stream>>>(rowptr, csr, (const int4*)bufA8, norm, bufB8, SCALE_R);
    gather_fp8<0><<<gridG, 256, 0, stream>>>(rowptr, csr, (const int4*)bufB8, norm, bufA8, SCALE_R);
    gather_fp8<1><<<gridG, 256, 0, stream>>>(rowptr, csr, (const int4*)bufA8, norm, bufH, invGR2);

    // ---- colsum of relu(h @ W2 + b2) ----
    hipMemsetAsync(colsum, 0, D * 4, stream);
    gemm2_mfma_colsum<<<250, 256, 0, stream>>>(bufH, Wt2, b2, colsum);

    // ---- final MLP + sigmoid ----
    final_mlp<<<1, 128, 0, stream>>>(colsum, Wf1, bf1, Wf2, bf2, out);
}